// Round 1
// baseline (945.071 us; speedup 1.0000x reference)
//
#include <hip/hip_runtime.h>
#include <math.h>

#define NG 512
#define NP 128
#define HID 64
#define KNN 24
#define NTOT (NG*NP)

__device__ __forceinline__ float elu_f(float v) { return v > 0.0f ? v : expm1f(v); }

// ---------------- encoder: h = elu(elu(x@we1+be1)@we2+be2); also writes batch ids ----------------
__global__ __launch_bounds__(256) void encoder_kernel(
    const float* __restrict__ x,
    const float* __restrict__ we1, const float* __restrict__ be1,
    const float* __restrict__ we2, const float* __restrict__ be2,
    float* __restrict__ h, float* __restrict__ out_batch)
{
    __shared__ __align__(16) float w2[64][64];
    __shared__ __align__(16) float h1[32][64];
    __shared__ float w1[4][64];
    __shared__ float b1s[64], b2s[64];
    const int t = threadIdx.x;
    const int nb = blockIdx.x * 32;

    for (int i = t; i < 4096; i += 256) w2[i >> 6][i & 63] = we2[i];
    if (t < 256) w1[t >> 6][t & 63] = we1[t];
    if (t < 64) { b1s[t] = be1[t]; b2s[t] = be2[t]; }
    __syncthreads();

    const int f = t & 63, nr = t >> 6;
    #pragma unroll
    for (int p = 0; p < 8; ++p) {
        const int nl = (p << 2) + nr;
        const int n = nb + nl;
        const float4 xv = ((const float4*)x)[n];
        float acc = b1s[f];
        acc += xv.x * w1[0][f];
        acc += xv.y * w1[1][f];
        acc += xv.z * w1[2][f];
        acc += xv.w * w1[3][f];
        h1[nl][f] = elu_f(acc);
    }
    __syncthreads();
    #pragma unroll
    for (int p = 0; p < 8; ++p) {
        const int nl = (p << 2) + nr;
        const int n = nb + nl;
        float a0 = b2s[f], a1 = 0.f, a2 = 0.f, a3 = 0.f;
        #pragma unroll
        for (int k = 0; k < 64; k += 4) {
            a0 += h1[nl][k]   * w2[k][f];
            a1 += h1[nl][k+1] * w2[k+1][f];
            a2 += h1[nl][k+2] * w2[k+2][f];
            a3 += h1[nl][k+3] * w2[k+3][f];
        }
        h[(size_t)n*64 + f] = elu_f((a0+a1)+(a2+a3));
    }
    if (t < 32) {
        const int n = nb + t;
        out_batch[n] = (float)(n >> 7);   // graph id = node/128
    }
}

// ---------------- preab: a = h@(wc_top-wc_bot)+bc ; b = h@wc_bot ----------------
__global__ __launch_bounds__(256) void preab_kernel(
    const float* __restrict__ h,
    const float* __restrict__ wc, const float* __restrict__ bc,
    float* __restrict__ a, float* __restrict__ b)
{
    __shared__ __align__(16) float wt[64][64];
    __shared__ __align__(16) float wb[64][64];
    __shared__ __align__(16) float hs[32][64];
    __shared__ float bcs[64];
    const int t = threadIdx.x;
    const int nb = blockIdx.x * 32;

    for (int i = t; i < 4096; i += 256) {
        const float top = wc[i];
        const float bot = wc[4096 + i];
        wt[i >> 6][i & 63] = top - bot;
        wb[i >> 6][i & 63] = bot;
    }
    if (t < 64) bcs[t] = bc[t];
    for (int i = t; i < 512; i += 256)
        ((float4*)hs)[i] = ((const float4*)(h + (size_t)nb * 64))[i];
    __syncthreads();

    const int f = t & 63, nr = t >> 6;
    #pragma unroll
    for (int p = 0; p < 8; ++p) {
        const int nl = (p << 2) + nr;
        float aa = bcs[f];
        float bb = 0.0f;
        #pragma unroll
        for (int k = 0; k < 64; ++k) {
            const float hv = hs[nl][k];
            aa += hv * wt[k][f];
            bb += hv * wb[k][f];
        }
        a[(size_t)(nb + nl)*64 + f] = aa;
        b[(size_t)(nb + nl)*64 + f] = bb;
    }
}

// ---------------- conv: per-graph kNN + max-aggregation.  out_i = elu(a_i + max_{j in knn(i)} b_j) ----------------
__global__ __launch_bounds__(256) void conv_kernel(
    const float* __restrict__ h,
    const float* __restrict__ a,
    const float* __restrict__ b,
    float* __restrict__ out)
{
    // xs row stride 68 floats: 16B-aligned rows, breaks the 64-float power-of-2 bank stride
    __shared__ __align__(16) float xs[128][68];     // 34816 B (reused for b in phase 2)
    __shared__ float sq[128];                        //   512 B
    __shared__ unsigned mkey[128][49];               // 25088 B (pad 49 -> conflict-free)
    __shared__ unsigned char nnidx[128][KNN];        //  3072 B   == 63488 B total (<64KB, 2 blk/CU)
    const int g = blockIdx.x;
    const int t = threadIdx.x;
    const float* __restrict__ hg = h + (size_t)g * (NP*HID);

    for (int i = t; i < 2048; i += 256) {
        const int row = i >> 4, c4 = (i & 15) << 2;
        *(float4*)&xs[row][c4] = ((const float4*)hg)[i];
    }
    __syncthreads();

    if (t < 128) {
        float s0=0.f,s1=0.f,s2=0.f,s3=0.f;
        #pragma unroll
        for (int k = 0; k < 64; k += 4) {
            s0 += xs[t][k]  *xs[t][k];
            s1 += xs[t][k+1]*xs[t][k+1];
            s2 += xs[t][k+2]*xs[t][k+2];
            s3 += xs[t][k+3]*xs[t][k+3];
        }
        sq[t] = (s0+s1)+(s2+s3);
    }
    __syncthreads();

    // phase: distances + per-half top-K (thread (i,half) scans 64 columns)
    {
        const int i = t & 127;
        const int half = t >> 7;
        float xi[64];
        #pragma unroll
        for (int k = 0; k < 16; ++k) {
            const float4 v = *(const float4*)&xs[i][k << 2];
            xi[4*k] = v.x; xi[4*k+1] = v.y; xi[4*k+2] = v.z; xi[4*k+3] = v.w;
        }
        unsigned bk[KNN];
        #pragma unroll
        for (int s = 0; s < KNN; ++s) bk[s] = 0xFFFFFFFFu;
        const float sqi = sq[i];
        const int j0 = half << 6;
        #pragma unroll 1
        for (int jj = 0; jj < 64; ++jj) {
            const int j = j0 + jj;
            float d0=0.f,d1=0.f,d2=0.f,d3=0.f;
            #pragma unroll
            for (int k = 0; k < 64; k += 4) {
                d0 += xi[k]   * xs[j][k];
                d1 += xi[k+1] * xs[j][k+1];
                d2 += xi[k+2] * xs[j][k+2];
                d3 += xi[k+3] * xs[j][k+3];
            }
            const float dot = (d0+d1)+(d2+d3);
            float d = sqi + sq[j] - 2.0f*dot;
            d = fmaxf(d, 0.0f);                      // keep float-bit ordering valid as uint
            const unsigned key = (__float_as_uint(d) & 0xFFFFFF80u) | (unsigned)j;
            if (key < bk[KNN-1]) {
                unsigned ck = key;
                #pragma unroll
                for (int s = 0; s < KNN; ++s) {
                    const unsigned os = bk[s];
                    const bool sw = ck < os;
                    bk[s] = sw ? ck : os;
                    ck   = sw ? os : ck;
                }
            }
        }
        #pragma unroll
        for (int s = 0; s < KNN; ++s) mkey[i][half*KNN + s] = bk[s];
    }
    __syncthreads();

    // merge the two half-lists (48 -> 24) per row
    if (t < 128) {
        unsigned bk[KNN];
        #pragma unroll
        for (int s = 0; s < KNN; ++s) bk[s] = 0xFFFFFFFFu;
        #pragma unroll 1
        for (int c = 0; c < 2*KNN; ++c) {
            const unsigned key = mkey[t][c];
            if (key < bk[KNN-1]) {
                unsigned ck = key;
                #pragma unroll
                for (int s = 0; s < KNN; ++s) {
                    const unsigned os = bk[s];
                    const bool sw = ck < os;
                    bk[s] = sw ? ck : os;
                    ck   = sw ? os : ck;
                }
            }
        }
        #pragma unroll
        for (int s = 0; s < KNN; ++s) nnidx[t][s] = (unsigned char)(bk[s] & 127u);
    }
    __syncthreads();

    // overwrite xs with this graph's b rows
    for (int i = t; i < 2048; i += 256) {
        const int row = i >> 4, c4 = (i & 15) << 2;
        *(float4*)&xs[row][c4] = ((const float4*)(b + (size_t)g*(NP*HID)))[i];
    }
    __syncthreads();

    // aggregation: out_i[f] = elu(a_i[f] + max_j b_j[f])
    {
        const int f = t & 63, i0 = t >> 6;
        const float* __restrict__ ag = a + (size_t)g*(NP*HID);
        float* __restrict__ og = out + (size_t)g*(NP*HID);
        #pragma unroll 4
        for (int p = 0; p < 32; ++p) {
            const int i = (p << 2) + i0;
            float m = -1e30f;
            #pragma unroll
            for (int n = 0; n < KNN; ++n) {
                const int j = nnidx[i][n];
                m = fmaxf(m, xs[j][f]);
            }
            og[(size_t)i*64 + f] = elu_f(ag[(size_t)i*64 + f] + m);
        }
    }
}

// ---------------- head: sum-pool over nodes + 5-layer MLP ----------------
__global__ __launch_bounds__(64) void head_kernel(
    const float* __restrict__ h,
    const float* __restrict__ wo1, const float* __restrict__ bo1,
    const float* __restrict__ wo2, const float* __restrict__ bo2,
    const float* __restrict__ wo3, const float* __restrict__ bo3,
    const float* __restrict__ wo4, const float* __restrict__ bo4,
    const float* __restrict__ wo5, const float* __restrict__ bo5,
    float* __restrict__ outp)
{
    __shared__ float pooled[64];
    __shared__ float o1[64];
    __shared__ float o2[32];
    __shared__ float o3[32];
    __shared__ float o4[8];
    const int g = blockIdx.x, t = threadIdx.x;
    const float* __restrict__ hg = h + (size_t)g * (NP*HID);

    float s = 0.0f;
    #pragma unroll 4
    for (int n = 0; n < NP; ++n) s += hg[n*64 + t];
    pooled[t] = s;
    __syncthreads();
    {
        float acc = bo1[t];
        #pragma unroll
        for (int k = 0; k < 64; ++k) acc += pooled[k] * wo1[k*64 + t];
        o1[t] = elu_f(acc);
    }
    __syncthreads();
    if (t < 32) {
        float acc = bo2[t];
        #pragma unroll
        for (int k = 0; k < 64; ++k) acc += o1[k] * wo2[k*32 + t];
        o2[t] = elu_f(acc);
    }
    __syncthreads();
    if (t < 32) {
        float acc = bo3[t];
        #pragma unroll
        for (int k = 0; k < 32; ++k) acc += o2[k] * wo3[k*32 + t];
        o3[t] = elu_f(acc);
    }
    __syncthreads();
    if (t < 8) {
        float acc = bo4[t];
        #pragma unroll
        for (int k = 0; k < 32; ++k) acc += o3[k] * wo4[k*8 + t];
        o4[t] = elu_f(acc);
    }
    __syncthreads();
    if (t == 0) {
        float acc = bo5[0];
        #pragma unroll
        for (int k = 0; k < 8; ++k) acc += o4[k] * wo5[k];
        outp[g] = acc;
    }
}

extern "C" void kernel_launch(void* const* d_in, const int* in_sizes, int n_in,
                              void* d_out, int out_size, void* d_ws, size_t ws_size,
                              hipStream_t stream) {
    const float* x_pf = (const float*)d_in[0];
    // d_in[1] = batch_pf (regenerated on device, not read)
    const float* we1 = (const float*)d_in[2];
    const float* be1 = (const float*)d_in[3];
    const float* we2 = (const float*)d_in[4];
    const float* be2 = (const float*)d_in[5];
    const float* wc1 = (const float*)d_in[6];
    const float* bc1 = (const float*)d_in[7];
    const float* wc2 = (const float*)d_in[8];
    const float* bc2 = (const float*)d_in[9];
    const float* wc3 = (const float*)d_in[10];
    const float* bc3 = (const float*)d_in[11];
    const float* wo1 = (const float*)d_in[12];
    const float* bo1 = (const float*)d_in[13];
    const float* wo2 = (const float*)d_in[14];
    const float* bo2 = (const float*)d_in[15];
    const float* wo3 = (const float*)d_in[16];
    const float* bo3 = (const float*)d_in[17];
    const float* wo4 = (const float*)d_in[18];
    const float* bo4 = (const float*)d_in[19];
    const float* wo5 = (const float*)d_in[20];
    const float* bo5 = (const float*)d_in[21];

    float* out = (float*)d_out;           // [0:512) = graph outputs, [512:512+65536) = batch ids (as float)
    char* ws = (char*)d_ws;
    const size_t SZ = (size_t)NTOT * HID * sizeof(float);   // 16 MB per buffer
    float* h0 = (float*)(ws);
    float* h1 = (float*)(ws + SZ);
    float* aa = (float*)(ws + 2*SZ);
    float* bb = (float*)(ws + 3*SZ);

    encoder_kernel<<<NTOT/32, 256, 0, stream>>>(x_pf, we1, be1, we2, be2, h0, out + NG);

    preab_kernel<<<NTOT/32, 256, 0, stream>>>(h0, wc1, bc1, aa, bb);
    conv_kernel<<<NG, 256, 0, stream>>>(h0, aa, bb, h1);

    preab_kernel<<<NTOT/32, 256, 0, stream>>>(h1, wc2, bc2, aa, bb);
    conv_kernel<<<NG, 256, 0, stream>>>(h1, aa, bb, h0);

    preab_kernel<<<NTOT/32, 256, 0, stream>>>(h0, wc3, bc3, aa, bb);
    conv_kernel<<<NG, 256, 0, stream>>>(h0, aa, bb, h1);

    head_kernel<<<NG, 64, 0, stream>>>(h1, wo1, bo1, wo2, bo2, wo3, bo3, wo4, bo4, wo5, bo5, out);
}

// Round 2
// 424.674 us; speedup vs baseline: 2.2254x; 2.2254x over previous
//
#include <hip/hip_runtime.h>
#include <math.h>

#define NG 512
#define NP 128
#define HID 64
#define KNN 24
#define NTOT (NG*NP)

__device__ __forceinline__ float elu_f(float v) { return v > 0.0f ? v : expm1f(v); }

// ---------------- encoder: h = elu(elu(x@we1+be1)@we2+be2); also writes batch ids ----------------
// Layer-2 GEMM uses transposed weights in LDS: per 4k-chunk, 1 divergent b128
// weight read + 8 broadcast b128 h reads -> 32 FMA (VALU-bound, not LDS-bound).
__global__ __launch_bounds__(256) void encoder_kernel(
    const float* __restrict__ x,
    const float* __restrict__ we1, const float* __restrict__ be1,
    const float* __restrict__ we2, const float* __restrict__ be2,
    float* __restrict__ h, float* __restrict__ out_batch)
{
    __shared__ __align__(16) float w2T[64*68];    // transposed [f][k], stride 68 (16B-aligned rows)
    __shared__ __align__(16) float h1s[32*64];
    __shared__ float w1[4][64];
    __shared__ float b1s[64], b2s[64];
    const int t = threadIdx.x;
    const int nb = blockIdx.x * 32;

    for (int i = t; i < 4096; i += 256) {
        const int k = i >> 6, f = i & 63;
        w2T[f*68 + k] = we2[i];
    }
    if (t < 256) w1[t >> 6][t & 63] = we1[t];
    if (t < 64) { b1s[t] = be1[t]; b2s[t] = be2[t]; }
    __syncthreads();

    const int f = t & 63, rg = t >> 6;
    // layer 1 (x is [n][4])
    #pragma unroll
    for (int p = 0; p < 8; ++p) {
        const int nl = (p << 2) + rg;
        const float4 xv = ((const float4*)x)[nb + nl];
        float acc = b1s[f];
        acc = fmaf(xv.x, w1[0][f], acc);
        acc = fmaf(xv.y, w1[1][f], acc);
        acc = fmaf(xv.z, w1[2][f], acc);
        acc = fmaf(xv.w, w1[3][f], acc);
        h1s[nl*64 + f] = elu_f(acc);
    }
    __syncthreads();

    // layer 2: thread owns column f, 8 rows (rg*8 .. rg*8+7)
    float aa[8];
    #pragma unroll
    for (int p = 0; p < 8; ++p) aa[p] = b2s[f];
    const float4* wv = (const float4*)(w2T + f*68);
    #pragma unroll
    for (int kc = 0; kc < 16; ++kc) {
        const float4 w4 = wv[kc];
        #pragma unroll
        for (int p = 0; p < 8; ++p) {
            const float4 h4 = *(const float4*)(h1s + (rg*8 + p)*64 + kc*4);  // broadcast
            aa[p] = fmaf(h4.x, w4.x, aa[p]);
            aa[p] = fmaf(h4.y, w4.y, aa[p]);
            aa[p] = fmaf(h4.z, w4.z, aa[p]);
            aa[p] = fmaf(h4.w, w4.w, aa[p]);
        }
    }
    #pragma unroll
    for (int p = 0; p < 8; ++p) {
        const int n = nb + rg*8 + p;
        h[(size_t)n*64 + f] = elu_f(aa[p]);
    }
    if (t < 32) {
        const int n = nb + t;
        out_batch[n] = (float)(n >> 7);   // graph id = node/128
    }
}

// ---------------- preab: a = h@(wc_top-wc_bot)+bc ; b = h@wc_bot ----------------
// Same transposed-weight register-blocked structure: per 4k-chunk per thread:
// 2 divergent b128 weight reads + 8 broadcast b128 h reads -> 64 FMA.
__global__ __launch_bounds__(256) void preab_kernel(
    const float* __restrict__ h,
    const float* __restrict__ wc, const float* __restrict__ bc,
    float* __restrict__ a, float* __restrict__ b)
{
    __shared__ __align__(16) float wtT[64*68];    // (wc_top - wc_bot)^T [f][k]
    __shared__ __align__(16) float wbT[64*68];    // wc_bot^T [f][k]
    __shared__ __align__(16) float hs[32*64];
    __shared__ float bcs[64];
    const int t = threadIdx.x;
    const int nb = blockIdx.x * 32;

    for (int i = t; i < 4096; i += 256) {
        const int k = i >> 6, f = i & 63;
        const float top = wc[i];
        const float bot = wc[4096 + i];
        wtT[f*68 + k] = top - bot;
        wbT[f*68 + k] = bot;
    }
    if (t < 64) bcs[t] = bc[t];
    for (int i = t; i < 512; i += 256)
        ((float4*)hs)[i] = ((const float4*)(h + (size_t)nb * 64))[i];
    __syncthreads();

    const int f = t & 63, rg = t >> 6;
    float aa[8], bb[8];
    #pragma unroll
    for (int p = 0; p < 8; ++p) { aa[p] = bcs[f]; bb[p] = 0.0f; }
    const float4* wtv = (const float4*)(wtT + f*68);
    const float4* wbv = (const float4*)(wbT + f*68);
    #pragma unroll
    for (int kc = 0; kc < 16; ++kc) {
        const float4 wt = wtv[kc];
        const float4 wb = wbv[kc];
        #pragma unroll
        for (int p = 0; p < 8; ++p) {
            const float4 h4 = *(const float4*)(hs + (rg*8 + p)*64 + kc*4);   // broadcast
            aa[p] = fmaf(h4.x, wt.x, aa[p]);
            aa[p] = fmaf(h4.y, wt.y, aa[p]);
            aa[p] = fmaf(h4.z, wt.z, aa[p]);
            aa[p] = fmaf(h4.w, wt.w, aa[p]);
            bb[p] = fmaf(h4.x, wb.x, bb[p]);
            bb[p] = fmaf(h4.y, wb.y, bb[p]);
            bb[p] = fmaf(h4.z, wb.z, bb[p]);
            bb[p] = fmaf(h4.w, wb.w, bb[p]);
        }
    }
    #pragma unroll
    for (int p = 0; p < 8; ++p) {
        const size_t n = (size_t)(nb + rg*8 + p);
        a[n*64 + f] = aa[p];
        b[n*64 + f] = bb[p];
    }
}

// ---------------- conv: per-graph kNN + max-aggregation.  out_i = elu(a_i + max_{j in knn(i)} b_j) ----------------
__global__ __launch_bounds__(256) void conv_kernel(
    const float* __restrict__ h,
    const float* __restrict__ a,
    const float* __restrict__ b,
    float* __restrict__ out)
{
    // xs row stride 68 floats: 16B-aligned rows, breaks the 64-float power-of-2 bank stride
    __shared__ __align__(16) float xs[128][68];     // 34816 B (reused for b in phase 2)
    __shared__ float sq[128];                        //   512 B
    __shared__ unsigned mkey[128][49];               // 25088 B (pad 49 -> conflict-free)
    __shared__ unsigned char nnidx[128][KNN];        //  3072 B   == 63488 B total (<64KB, 2 blk/CU)
    const int g = blockIdx.x;
    const int t = threadIdx.x;
    const float* __restrict__ hg = h + (size_t)g * (NP*HID);

    for (int i = t; i < 2048; i += 256) {
        const int row = i >> 4, c4 = (i & 15) << 2;
        *(float4*)&xs[row][c4] = ((const float4*)hg)[i];
    }
    __syncthreads();

    if (t < 128) {
        float s0=0.f,s1=0.f,s2=0.f,s3=0.f;
        #pragma unroll
        for (int kc = 0; kc < 16; ++kc) {
            const float4 v = *(const float4*)&xs[t][kc << 2];
            s0 = fmaf(v.x, v.x, s0);
            s1 = fmaf(v.y, v.y, s1);
            s2 = fmaf(v.z, v.z, s2);
            s3 = fmaf(v.w, v.w, s3);
        }
        sq[t] = (s0+s1)+(s2+s3);
    }
    __syncthreads();

    // phase: distances + per-half top-K (thread (i,half) scans 64 columns; j wave-uniform)
    {
        const int i = t & 127;
        const int half = t >> 7;
        float4 xiv[16];
        #pragma unroll
        for (int kc = 0; kc < 16; ++kc) xiv[kc] = *(const float4*)&xs[i][kc << 2];
        unsigned bk[KNN];
        #pragma unroll
        for (int s = 0; s < KNN; ++s) bk[s] = 0xFFFFFFFFu;
        const float sqi = sq[i];
        const int j0 = half << 6;
        #pragma unroll 1
        for (int jj = 0; jj < 64; ++jj) {
            const int j = j0 + jj;
            const float4* xr = (const float4*)&xs[j][0];   // wave-uniform -> broadcast b128
            float d0=0.f,d1=0.f,d2=0.f,d3=0.f;
            #pragma unroll
            for (int kc = 0; kc < 16; ++kc) {
                const float4 v = xr[kc];
                d0 = fmaf(xiv[kc].x, v.x, d0);
                d1 = fmaf(xiv[kc].y, v.y, d1);
                d2 = fmaf(xiv[kc].z, v.z, d2);
                d3 = fmaf(xiv[kc].w, v.w, d3);
            }
            const float dot = (d0+d1)+(d2+d3);
            float d = sqi + sq[j] - 2.0f*dot;
            d = fmaxf(d, 0.0f);                      // keep float-bit ordering valid as uint
            const unsigned key = (__float_as_uint(d) & 0xFFFFFF80u) | (unsigned)j;
            if (key < bk[KNN-1]) {
                unsigned ck = key;
                #pragma unroll
                for (int s = 0; s < KNN; ++s) {
                    const unsigned os = bk[s];
                    const bool sw = ck < os;
                    bk[s] = sw ? ck : os;
                    ck   = sw ? os : ck;
                }
            }
        }
        #pragma unroll
        for (int s = 0; s < KNN; ++s) mkey[i][half*KNN + s] = bk[s];
    }
    __syncthreads();

    // merge the two half-lists (48 -> 24) per row
    if (t < 128) {
        unsigned bk[KNN];
        #pragma unroll
        for (int s = 0; s < KNN; ++s) bk[s] = 0xFFFFFFFFu;
        #pragma unroll 1
        for (int c = 0; c < 2*KNN; ++c) {
            const unsigned key = mkey[t][c];
            if (key < bk[KNN-1]) {
                unsigned ck = key;
                #pragma unroll
                for (int s = 0; s < KNN; ++s) {
                    const unsigned os = bk[s];
                    const bool sw = ck < os;
                    bk[s] = sw ? ck : os;
                    ck   = sw ? os : ck;
                }
            }
        }
        #pragma unroll
        for (int s = 0; s < KNN; ++s) nnidx[t][s] = (unsigned char)(bk[s] & 127u);
    }
    __syncthreads();

    // overwrite xs with this graph's b rows
    for (int i = t; i < 2048; i += 256) {
        const int row = i >> 4, c4 = (i & 15) << 2;
        *(float4*)&xs[row][c4] = ((const float4*)(b + (size_t)g*(NP*HID)))[i];
    }
    __syncthreads();

    // aggregation: out_i[f] = elu(a_i[f] + max_j b_j[f])
    {
        const int f = t & 63, i0 = t >> 6;
        const float* __restrict__ ag = a + (size_t)g*(NP*HID);
        float* __restrict__ og = out + (size_t)g*(NP*HID);
        #pragma unroll 4
        for (int p = 0; p < 32; ++p) {
            const int i = (p << 2) + i0;
            float m = -1e30f;
            #pragma unroll
            for (int n = 0; n < KNN; ++n) {
                const int j = nnidx[i][n];
                m = fmaxf(m, xs[j][f]);
            }
            og[(size_t)i*64 + f] = elu_f(ag[(size_t)i*64 + f] + m);
        }
    }
}

// ---------------- head: sum-pool over nodes + 5-layer MLP ----------------
__global__ __launch_bounds__(256) void head_kernel(
    const float* __restrict__ h,
    const float* __restrict__ wo1, const float* __restrict__ bo1,
    const float* __restrict__ wo2, const float* __restrict__ bo2,
    const float* __restrict__ wo3, const float* __restrict__ bo3,
    const float* __restrict__ wo4, const float* __restrict__ bo4,
    const float* __restrict__ wo5, const float* __restrict__ bo5,
    float* __restrict__ outp)
{
    __shared__ float pool4[4][64];
    __shared__ float pooled[64];
    __shared__ float o1[64];
    __shared__ float o2[32];
    __shared__ float o3[32];
    __shared__ float o4[8];
    const int g = blockIdx.x, t = threadIdx.x;
    const int f = t & 63, q = t >> 6;
    const float* __restrict__ hg = h + (size_t)g * (NP*HID);

    float s = 0.0f;
    #pragma unroll 8
    for (int n = q; n < NP; n += 4) s += hg[n*64 + f];
    pool4[q][f] = s;
    __syncthreads();

    if (t < 64) {   // single wave: LDS RAW inside one wave needs no barrier
        pooled[t] = pool4[0][t] + pool4[1][t] + pool4[2][t] + pool4[3][t];
        {
            float acc = bo1[t];
            #pragma unroll
            for (int k = 0; k < 64; ++k) acc = fmaf(pooled[k], wo1[k*64 + t], acc);
            o1[t] = elu_f(acc);
        }
        if (t < 32) {
            float acc = bo2[t];
            #pragma unroll
            for (int k = 0; k < 64; ++k) acc = fmaf(o1[k], wo2[k*32 + t], acc);
            o2[t] = elu_f(acc);
        }
        if (t < 32) {
            float acc = bo3[t];
            #pragma unroll
            for (int k = 0; k < 32; ++k) acc = fmaf(o2[k], wo3[k*32 + t], acc);
            o3[t] = elu_f(acc);
        }
        if (t < 8) {
            float acc = bo4[t];
            #pragma unroll
            for (int k = 0; k < 32; ++k) acc = fmaf(o3[k], wo4[k*8 + t], acc);
            o4[t] = elu_f(acc);
        }
        if (t == 0) {
            float acc = bo5[0];
            #pragma unroll
            for (int k = 0; k < 8; ++k) acc = fmaf(o4[k], wo5[k], acc);
            outp[g] = acc;
        }
    }
}

extern "C" void kernel_launch(void* const* d_in, const int* in_sizes, int n_in,
                              void* d_out, int out_size, void* d_ws, size_t ws_size,
                              hipStream_t stream) {
    const float* x_pf = (const float*)d_in[0];
    // d_in[1] = batch_pf (regenerated on device, not read)
    const float* we1 = (const float*)d_in[2];
    const float* be1 = (const float*)d_in[3];
    const float* we2 = (const float*)d_in[4];
    const float* be2 = (const float*)d_in[5];
    const float* wc1 = (const float*)d_in[6];
    const float* bc1 = (const float*)d_in[7];
    const float* wc2 = (const float*)d_in[8];
    const float* bc2 = (const float*)d_in[9];
    const float* wc3 = (const float*)d_in[10];
    const float* bc3 = (const float*)d_in[11];
    const float* wo1 = (const float*)d_in[12];
    const float* bo1 = (const float*)d_in[13];
    const float* wo2 = (const float*)d_in[14];
    const float* bo2 = (const float*)d_in[15];
    const float* wo3 = (const float*)d_in[16];
    const float* bo3 = (const float*)d_in[17];
    const float* wo4 = (const float*)d_in[18];
    const float* bo4 = (const float*)d_in[19];
    const float* wo5 = (const float*)d_in[20];
    const float* bo5 = (const float*)d_in[21];

    float* out = (float*)d_out;           // [0:512) = graph outputs, [512:512+65536) = batch ids (as float)
    char* ws = (char*)d_ws;
    const size_t SZ = (size_t)NTOT * HID * sizeof(float);   // 16 MB per buffer
    float* h0 = (float*)(ws);
    float* h1 = (float*)(ws + SZ);
    float* aa = (float*)(ws + 2*SZ);
    float* bb = (float*)(ws + 3*SZ);

    encoder_kernel<<<NTOT/32, 256, 0, stream>>>(x_pf, we1, be1, we2, be2, h0, out + NG);

    preab_kernel<<<NTOT/32, 256, 0, stream>>>(h0, wc1, bc1, aa, bb);
    conv_kernel<<<NG, 256, 0, stream>>>(h0, aa, bb, h1);

    preab_kernel<<<NTOT/32, 256, 0, stream>>>(h1, wc2, bc2, aa, bb);
    conv_kernel<<<NG, 256, 0, stream>>>(h1, aa, bb, h0);

    preab_kernel<<<NTOT/32, 256, 0, stream>>>(h0, wc3, bc3, aa, bb);
    conv_kernel<<<NG, 256, 0, stream>>>(h0, aa, bb, h1);

    head_kernel<<<NG, 256, 0, stream>>>(h1, wo1, bo1, wo2, bo2, wo3, bo3, wo4, bo4, wo5, bo5, out);
}

// Round 3
// 317.739 us; speedup vs baseline: 2.9744x; 1.3365x over previous
//
#include <hip/hip_runtime.h>
#include <math.h>

#define NG 512
#define NP 128
#define HID 64
#define KNN 24
#define NTOT (NG*NP)

typedef __attribute__((ext_vector_type(8)))  short  short8;
typedef __attribute__((ext_vector_type(16))) float  floatx16;

__device__ __forceinline__ float elu_f(float v) { return v > 0.0f ? v : expm1f(v); }

__device__ __forceinline__ void split_bf16(float x, unsigned short& hb, unsigned short& lb) {
    unsigned u = __float_as_uint(x);
    unsigned h = (u + 0x7FFFu + ((u >> 16) & 1u)) >> 16;
    hb = (unsigned short)h;
    float hf = __uint_as_float(h << 16);
    float lo = x - hf;
    unsigned v = __float_as_uint(lo);
    lb = (unsigned short)((v + 0x7FFFu + ((v >> 16) & 1u)) >> 16);
}

// ---------------- pack weights into MFMA-B-fragment-ready hi/lo bf16 layout ----------------
// W = [wt | wb] (64 k x 128 col), wt = wc_top - wc_bot, wb = wc_bot.
// ushort index within layer: part*8192 + (ch*128 + col)*8 + e, ch = c*2+half, k = c*16+half*8+e.
__global__ __launch_bounds__(256) void pack_w(
    const float* __restrict__ wc1, const float* __restrict__ wc2, const float* __restrict__ wc3,
    unsigned short* __restrict__ wp)
{
    const int n = blockIdx.x*256 + threadIdx.x;      // 0..24575
    const int layer = n >> 13;
    const int r = n & 8191;
    const int e = r & 7, j = (r >> 3) & 127, ch = r >> 10;
    const int k = (ch >> 1)*16 + (ch & 1)*8 + e;
    const float* wc = (layer == 0) ? wc1 : ((layer == 1) ? wc2 : wc3);
    float w;
    if (j < 64) w = wc[k*64 + j] - wc[(k+64)*64 + j];
    else        w = wc[(k+64)*64 + (j-64)];
    unsigned short hb, lb;
    split_bf16(w, hb, lb);
    unsigned short* base = wp + layer*16384;
    base[r] = hb;
    base[8192 + r] = lb;
}

// ---------------- encoder: h = elu(elu(x@we1+be1)@we2+be2); also writes batch ids ----------------
__global__ __launch_bounds__(256) void encoder_kernel(
    const float* __restrict__ x,
    const float* __restrict__ we1, const float* __restrict__ be1,
    const float* __restrict__ we2, const float* __restrict__ be2,
    float* __restrict__ h, float* __restrict__ out_batch)
{
    __shared__ __align__(16) float w2T[64*68];    // transposed [f][k], stride 68
    __shared__ __align__(16) float h1s[32*64];
    __shared__ float w1[4][64];
    __shared__ float b1s[64], b2s[64];
    const int t = threadIdx.x;
    const int nb = blockIdx.x * 32;

    for (int i = t; i < 4096; i += 256) {
        const int k = i >> 6, f = i & 63;
        w2T[f*68 + k] = we2[i];
    }
    if (t < 256) w1[t >> 6][t & 63] = we1[t];
    if (t < 64) { b1s[t] = be1[t]; b2s[t] = be2[t]; }
    __syncthreads();

    const int f = t & 63, rg = t >> 6;
    #pragma unroll
    for (int p = 0; p < 8; ++p) {
        const int nl = (p << 2) + rg;
        const float4 xv = ((const float4*)x)[nb + nl];
        float acc = b1s[f];
        acc = fmaf(xv.x, w1[0][f], acc);
        acc = fmaf(xv.y, w1[1][f], acc);
        acc = fmaf(xv.z, w1[2][f], acc);
        acc = fmaf(xv.w, w1[3][f], acc);
        h1s[nl*64 + f] = elu_f(acc);
    }
    __syncthreads();

    float aa[8];
    #pragma unroll
    for (int p = 0; p < 8; ++p) aa[p] = b2s[f];
    const float4* wv = (const float4*)(w2T + f*68);
    #pragma unroll
    for (int kc = 0; kc < 16; ++kc) {
        const float4 w4 = wv[kc];
        #pragma unroll
        for (int p = 0; p < 8; ++p) {
            const float4 h4 = *(const float4*)(h1s + (rg*8 + p)*64 + kc*4);
            aa[p] = fmaf(h4.x, w4.x, aa[p]);
            aa[p] = fmaf(h4.y, w4.y, aa[p]);
            aa[p] = fmaf(h4.z, w4.z, aa[p]);
            aa[p] = fmaf(h4.w, w4.w, aa[p]);
        }
    }
    #pragma unroll
    for (int p = 0; p < 8; ++p) {
        const int n = nb + rg*8 + p;
        h[(size_t)n*64 + f] = elu_f(aa[p]);
    }
    if (t < 32) {
        const int n = nb + t;
        out_batch[n] = (float)(n >> 7);
    }
}

// ---------------- fused conv: hiLo split + ab-GEMM (MFMA) + Gram (MFMA) + kNN + max-agg ----------------
// Arena: keys[128][36] u32 @0 (18432) | hiLo[128][136] bf16 @18432 (34816; later mkey[128][49] then bs[128][68])
//        | sq[128] f32 @53248 | nnw[128][6] u32 @53760.  Total 56832 B -> 2 blocks/CU.
__global__ __launch_bounds__(256) void conv_fused(
    float* __restrict__ h,                       // in/out [512][128][64] (in-place safe: per-graph block)
    const unsigned short* __restrict__ wp,       // this layer's packed weights (16384 ushorts)
    const float* __restrict__ bc,
    float* __restrict__ ab)                      // scratch [512][128][128]: cols 0..63 = a, 64..127 = b
{
    __shared__ __align__(16) char arena[56832];
    unsigned*        keys = (unsigned*)arena;
    unsigned short*  hilo = (unsigned short*)(arena + 18432);
    float*           sqs  = (float*)(arena + 53248);
    unsigned*        nnw  = (unsigned*)(arena + 53760);

    const int g = blockIdx.x;
    const int t = threadIdx.x;
    const int lane = t & 63, w = t >> 6;
    const int lj = lane & 31, half = lane >> 5;
    float* __restrict__ hg = h + (size_t)g * (NP*HID);
    float* __restrict__ abg = ab + (size_t)g * (NP*128);

    // ---- phase 0: stage h -> hi/lo bf16 + sq ----
    {
        const int r = t >> 1, c0 = (t & 1) * 32;
        const float4* src = (const float4*)(hg + r*64 + c0);
        unsigned hh[16], llo[16];
        float s = 0.0f;
        #pragma unroll
        for (int q = 0; q < 8; ++q) {
            const float4 v = src[q];
            s = fmaf(v.x, v.x, s); s = fmaf(v.y, v.y, s);
            s = fmaf(v.z, v.z, s); s = fmaf(v.w, v.w, s);
            unsigned short hx, lx, hy, ly, hz, lz, hw2, lw2;
            split_bf16(v.x, hx, lx); split_bf16(v.y, hy, ly);
            split_bf16(v.z, hz, lz); split_bf16(v.w, hw2, lw2);
            hh[q*2]   = (unsigned)hx | ((unsigned)hy << 16);
            hh[q*2+1] = (unsigned)hz | ((unsigned)hw2 << 16);
            llo[q*2]   = (unsigned)lx | ((unsigned)ly << 16);
            llo[q*2+1] = (unsigned)lz | ((unsigned)lw2 << 16);
        }
        uint4* dh = (uint4*)(hilo + r*136 + c0);
        uint4* dl = (uint4*)(hilo + r*136 + 64 + c0);
        #pragma unroll
        for (int q = 0; q < 4; ++q) {
            dh[q] = make_uint4(hh[q*4], hh[q*4+1], hh[q*4+2], hh[q*4+3]);
            dl[q] = make_uint4(llo[q*4], llo[q*4+1], llo[q*4+2], llo[q*4+3]);
        }
        s += __shfl_xor(s, 1);
        if ((t & 1) == 0) sqs[r] = s;
    }
    __syncthreads();

    // ---- phase 2: ab-GEMM via MFMA: out = hiLo @ Wpack (+bc on a-cols), write to global ab ----
    #pragma unroll 1
    for (int jt = 0; jt < 4; ++jt) {
        floatx16 acc = {0.f,0.f,0.f,0.f,0.f,0.f,0.f,0.f,0.f,0.f,0.f,0.f,0.f,0.f,0.f,0.f};
        #pragma unroll
        for (int p = 0; p < 3; ++p) {                 // (A,B): (hi,hi),(hi,lo),(lo,hi)
            const int Asel = (p == 2) ? 64 : 0;
            const int part = (p == 1) ? 1 : 0;
            #pragma unroll
            for (int c = 0; c < 4; ++c) {
                const short8 af = *(const short8*)(hilo + (w*32 + lj)*136 + Asel + c*16 + half*8);
                const short8 bf = *(const short8*)((const short*)wp + part*8192 + (((c*2 + half)*128) + jt*32 + lj)*8);
                acc = __builtin_amdgcn_mfma_f32_32x32x16_bf16(af, bf, acc, 0, 0, 0);
            }
        }
        const int col = jt*32 + lj;
        const float bias = (jt < 2) ? bc[col] : 0.0f;
        #pragma unroll
        for (int reg = 0; reg < 16; ++reg) {
            const int row = (reg & 3) + 8*(reg >> 2) + 4*half + w*32;
            abg[(size_t)row*128 + col] = acc[reg] + bias;
        }
    }

    // ---- phase 3: Gram strips via MFMA + per-strip top-k insertion ----
    unsigned bk[KNN];
    #pragma unroll
    for (int s = 0; s < KNN; ++s) bk[s] = 0xFFFFFFFFu;
    const int i2 = t & 127, jh = t >> 7;

    #pragma unroll 1
    for (int jt = 0; jt < 4; ++jt) {
        floatx16 acc = {0.f,0.f,0.f,0.f,0.f,0.f,0.f,0.f,0.f,0.f,0.f,0.f,0.f,0.f,0.f,0.f};
        #pragma unroll
        for (int p = 0; p < 3; ++p) {
            const int Asel = (p == 2) ? 64 : 0;
            const int Bsel = (p == 1) ? 64 : 0;
            #pragma unroll
            for (int c = 0; c < 4; ++c) {
                const short8 af = *(const short8*)(hilo + (w*32 + lj)*136 + Asel + c*16 + half*8);
                const short8 bf = *(const short8*)(hilo + (jt*32 + lj)*136 + Bsel + c*16 + half*8);
                acc = __builtin_amdgcn_mfma_f32_32x32x16_bf16(af, bf, acc, 0, 0, 0);
            }
        }
        const unsigned jg = (unsigned)(jt*32 + lj);
        const float sqj = sqs[jg];
        #pragma unroll
        for (int reg = 0; reg < 16; ++reg) {
            const int i = (reg & 3) + 8*(reg >> 2) + 4*half + w*32;
            float d = sqs[i] + sqj - 2.0f*acc[reg];
            d = fmaxf(d, 0.0f);
            keys[i*36 + lj] = (__float_as_uint(d) & 0xFFFFFF80u) | jg;
        }
        __syncthreads();
        // insertion: thread (i2, jh) scans its 16 keys of this strip
        const uint4* kp = (const uint4*)(keys + i2*36 + jh*16);
        #pragma unroll
        for (int c = 0; c < 4; ++c) {
            const uint4 kk = kp[c];
            const unsigned cand[4] = {kk.x, kk.y, kk.z, kk.w};
            #pragma unroll
            for (int e = 0; e < 4; ++e) {
                const unsigned key = cand[e];
                if (key < bk[KNN-1]) {
                    unsigned ck = key;
                    #pragma unroll
                    for (int s = 0; s < KNN; ++s) {
                        const unsigned os = bk[s];
                        const bool sw = ck < os;
                        bk[s] = sw ? ck : os;
                        ck   = sw ? os : ck;
                    }
                }
            }
        }
        __syncthreads();
    }

    // ---- phase 4: merge half-lists (hiLo dead -> mkey aliases it) ----
    unsigned* mkey = (unsigned*)(arena + 18432);   // [128][49]
    #pragma unroll
    for (int s = 0; s < KNN; ++s) mkey[i2*49 + jh*24 + s] = bk[s];
    __syncthreads();
    if (t < 128) {
        unsigned bm[KNN];
        #pragma unroll
        for (int s = 0; s < KNN; ++s) bm[s] = 0xFFFFFFFFu;
        #pragma unroll 1
        for (int c = 0; c < 2*KNN; ++c) {
            const unsigned key = mkey[t*49 + c];
            if (key < bm[KNN-1]) {
                unsigned ck = key;
                #pragma unroll
                for (int s = 0; s < KNN; ++s) {
                    const unsigned os = bm[s];
                    const bool sw = ck < os;
                    bm[s] = sw ? ck : os;
                    ck   = sw ? os : ck;
                }
            }
        }
        #pragma unroll
        for (int c = 0; c < 6; ++c) {
            nnw[t*6 + c] = (bm[c*4] & 127u) | ((bm[c*4+1] & 127u) << 8)
                         | ((bm[c*4+2] & 127u) << 16) | ((bm[c*4+3] & 127u) << 24);
        }
    }
    __syncthreads();

    // ---- phase 5: load b (ab cols 64..127) into LDS, aggregate out = elu(a + max_nn b) ----
    float* bs = (float*)(arena + 18432);           // [128][68]
    {
        const int r = t >> 1, c0 = (t & 1) * 32;
        const float4* bsrc = (const float4*)(abg + (size_t)r*128 + 64 + c0);
        float4* bdst = (float4*)(bs + r*68 + c0);
        #pragma unroll
        for (int q = 0; q < 8; ++q) bdst[q] = bsrc[q];
    }
    __syncthreads();
    {
        const int q = lane >> 4, fq = lane & 15;
        #pragma unroll 1
        for (int rg = 0; rg < 8; ++rg) {
            const int row = w*32 + rg*4 + q;
            float4 m = make_float4(-1e30f, -1e30f, -1e30f, -1e30f);
            #pragma unroll
            for (int c = 0; c < 6; ++c) {
                const unsigned pk = nnw[row*6 + c];
                #pragma unroll
                for (int e = 0; e < 4; ++e) {
                    const int j = (pk >> (8*e)) & 127;
                    const float4 v = *(const float4*)(bs + j*68 + fq*4);
                    m.x = fmaxf(m.x, v.x); m.y = fmaxf(m.y, v.y);
                    m.z = fmaxf(m.z, v.z); m.w = fmaxf(m.w, v.w);
                }
            }
            const float4 av = *(const float4*)(abg + (size_t)row*128 + fq*4);
            float4 o;
            o.x = elu_f(av.x + m.x); o.y = elu_f(av.y + m.y);
            o.z = elu_f(av.z + m.z); o.w = elu_f(av.w + m.w);
            *(float4*)(hg + (size_t)row*64 + fq*4) = o;
        }
    }
}

// ---------------- head: sum-pool over nodes + 5-layer MLP ----------------
__global__ __launch_bounds__(256) void head_kernel(
    const float* __restrict__ h,
    const float* __restrict__ wo1, const float* __restrict__ bo1,
    const float* __restrict__ wo2, const float* __restrict__ bo2,
    const float* __restrict__ wo3, const float* __restrict__ bo3,
    const float* __restrict__ wo4, const float* __restrict__ bo4,
    const float* __restrict__ wo5, const float* __restrict__ bo5,
    float* __restrict__ outp)
{
    __shared__ float pool4[4][64];
    __shared__ float pooled[64];
    __shared__ float o1[64];
    __shared__ float o2[32];
    __shared__ float o3[32];
    __shared__ float o4[8];
    const int g = blockIdx.x, t = threadIdx.x;
    const int f = t & 63, q = t >> 6;
    const float* __restrict__ hg = h + (size_t)g * (NP*HID);

    float s = 0.0f;
    #pragma unroll 8
    for (int n = q; n < NP; n += 4) s += hg[n*64 + f];
    pool4[q][f] = s;
    __syncthreads();

    if (t < 64) {
        pooled[t] = pool4[0][t] + pool4[1][t] + pool4[2][t] + pool4[3][t];
        {
            float acc = bo1[t];
            #pragma unroll
            for (int k = 0; k < 64; ++k) acc = fmaf(pooled[k], wo1[k*64 + t], acc);
            o1[t] = elu_f(acc);
        }
        if (t < 32) {
            float acc = bo2[t];
            #pragma unroll
            for (int k = 0; k < 64; ++k) acc = fmaf(o1[k], wo2[k*32 + t], acc);
            o2[t] = elu_f(acc);
        }
        if (t < 32) {
            float acc = bo3[t];
            #pragma unroll
            for (int k = 0; k < 32; ++k) acc = fmaf(o2[k], wo3[k*32 + t], acc);
            o3[t] = elu_f(acc);
        }
        if (t < 8) {
            float acc = bo4[t];
            #pragma unroll
            for (int k = 0; k < 32; ++k) acc = fmaf(o3[k], wo4[k*8 + t], acc);
            o4[t] = elu_f(acc);
        }
        if (t == 0) {
            float acc = bo5[0];
            #pragma unroll
            for (int k = 0; k < 8; ++k) acc = fmaf(o4[k], wo5[k], acc);
            outp[g] = acc;
        }
    }
}

extern "C" void kernel_launch(void* const* d_in, const int* in_sizes, int n_in,
                              void* d_out, int out_size, void* d_ws, size_t ws_size,
                              hipStream_t stream) {
    const float* x_pf = (const float*)d_in[0];
    const float* we1 = (const float*)d_in[2];
    const float* be1 = (const float*)d_in[3];
    const float* we2 = (const float*)d_in[4];
    const float* be2 = (const float*)d_in[5];
    const float* wc1 = (const float*)d_in[6];
    const float* bc1 = (const float*)d_in[7];
    const float* wc2 = (const float*)d_in[8];
    const float* bc2 = (const float*)d_in[9];
    const float* wc3 = (const float*)d_in[10];
    const float* bc3 = (const float*)d_in[11];
    const float* wo1 = (const float*)d_in[12];
    const float* bo1 = (const float*)d_in[13];
    const float* wo2 = (const float*)d_in[14];
    const float* bo2 = (const float*)d_in[15];
    const float* wo3 = (const float*)d_in[16];
    const float* bo3 = (const float*)d_in[17];
    const float* wo4 = (const float*)d_in[18];
    const float* bo4 = (const float*)d_in[19];
    const float* wo5 = (const float*)d_in[20];
    const float* bo5 = (const float*)d_in[21];

    float* out = (float*)d_out;           // [0:512) outputs, [512:) batch ids (as float)
    char* ws = (char*)d_ws;
    float* h0 = (float*)(ws);                                    // 16 MB
    float* ab = (float*)(ws + (size_t)16*1024*1024);             // 32 MB
    unsigned short* wpack = (unsigned short*)(ws + (size_t)48*1024*1024);  // 96 KB

    pack_w<<<96, 256, 0, stream>>>(wc1, wc2, wc3, wpack);
    encoder_kernel<<<NTOT/32, 256, 0, stream>>>(x_pf, we1, be1, we2, be2, h0, out + NG);

    conv_fused<<<NG, 256, 0, stream>>>(h0, wpack,         bc1, ab);
    conv_fused<<<NG, 256, 0, stream>>>(h0, wpack + 16384, bc2, ab);
    conv_fused<<<NG, 256, 0, stream>>>(h0, wpack + 32768, bc3, ab);

    head_kernel<<<NG, 256, 0, stream>>>(h0, wo1, bo1, wo2, bo2, wo3, bo3, wo4, bo4, wo5, bo5, out);
}

// Round 4
// 265.055 us; speedup vs baseline: 3.5656x; 1.1988x over previous
//
#include <hip/hip_runtime.h>
#include <math.h>

#define NG 512
#define NP 128
#define HID 64
#define KNN 24
#define NTOT (NG*NP)

typedef __attribute__((ext_vector_type(8)))  short  short8;
typedef __attribute__((ext_vector_type(16))) float  floatx16;

__device__ __forceinline__ float elu_f(float v) { return v > 0.0f ? v : expm1f(v); }

__device__ __forceinline__ void split_bf16(float x, unsigned short& hb, unsigned short& lb) {
    unsigned u = __float_as_uint(x);
    unsigned h = (u + 0x7FFFu + ((u >> 16) & 1u)) >> 16;
    hb = (unsigned short)h;
    float hf = __uint_as_float(h << 16);
    float lo = x - hf;
    unsigned v = __float_as_uint(lo);
    lb = (unsigned short)((v + 0x7FFFu + ((v >> 16) & 1u)) >> 16);
}

// ---------------- pack weights into MFMA-B-fragment-ready hi/lo bf16 layout ----------------
// Region 1 (3 conv layers): W = [wt | wb] (64 k x 128 col). ushort idx within layer:
//   part*8192 + (ch*128 + col)*8 + e, ch = c*2+half, k = c*16+half*8+e.
// Region 2 (we2, 64 k x 64 col) at wp + 49152: part*4096 + (ch*64 + col)*8 + e.
__global__ __launch_bounds__(256) void pack_w(
    const float* __restrict__ wc1, const float* __restrict__ wc2, const float* __restrict__ wc3,
    const float* __restrict__ we2,
    unsigned short* __restrict__ wp)
{
    const int n = blockIdx.x*256 + threadIdx.x;      // 0..28671
    if (n < 24576) {
        const int layer = n >> 13;
        const int r = n & 8191;
        const int e = r & 7, j = (r >> 3) & 127, ch = r >> 10;
        const int k = (ch >> 1)*16 + (ch & 1)*8 + e;
        const float* wc = (layer == 0) ? wc1 : ((layer == 1) ? wc2 : wc3);
        float w;
        if (j < 64) w = wc[k*64 + j] - wc[(k+64)*64 + j];
        else        w = wc[(k+64)*64 + (j-64)];
        unsigned short hb, lb;
        split_bf16(w, hb, lb);
        unsigned short* base = wp + layer*16384;
        base[r] = hb;
        base[8192 + r] = lb;
    } else if (n < 24576 + 4096) {
        const int m = n - 24576;                      // 0..4095
        const int e = m & 7, col = (m >> 3) & 63, ch = m >> 9;
        const int k = (ch >> 1)*16 + (ch & 1)*8 + e;
        unsigned short hb, lb;
        split_bf16(we2[k*64 + col], hb, lb);
        unsigned short* base = wp + 49152;
        base[m] = hb;
        base[4096 + m] = lb;
    }
}

// ---------------- fused conv (+optional encoder): ----------------
// FIRST: x -> elu(x@we1+be1) -> (MFMA) elu(@we2+be2) -> hg; also writes batch ids.
// Then: hi/lo split + ab-GEMM (MFMA) + Gram (MFMA) + kNN + max-agg, out -> hg.
// Arena: keys[128][36] u32 @0 (18432; aliased by w-staging in FIRST prologue)
//        | hiLo[128][136] bf16 @18432 (34816; later mkey[128][49] then bs[128][68])
//        | sq[128] f32 @53248 | nnw[128][6] u32 @53760.  Total 56832 B -> 2 blocks/CU.
template <bool FIRST>
__global__ __launch_bounds__(256) void conv_fused(
    float* __restrict__ h,                       // in/out [512][128][64]
    const unsigned short* __restrict__ wp,       // this layer's packed conv weights
    const float* __restrict__ bc,
    float* __restrict__ ab,                      // scratch [512][128][128]: cols 0..63 = a, 64..127 = b
    const float* __restrict__ x,                 // FIRST only: [65536][4]
    const float* __restrict__ we1, const float* __restrict__ be1,
    const unsigned short* __restrict__ we2p,     // FIRST only: packed we2 (8192 ushorts)
    const float* __restrict__ be2,
    float* __restrict__ out_batch)               // FIRST only
{
    __shared__ __align__(16) char arena[56832];
    unsigned*        keys = (unsigned*)arena;
    unsigned short*  hilo = (unsigned short*)(arena + 18432);
    float*           sqs  = (float*)(arena + 53248);
    unsigned*        nnw  = (unsigned*)(arena + 53760);

    const int g = blockIdx.x;
    const int t = threadIdx.x;
    const int lane = t & 63, w = t >> 6;
    const int lj = lane & 31, half = lane >> 5;
    float* __restrict__ hg = h + (size_t)g * (NP*HID);
    float* __restrict__ abg = ab + (size_t)g * (NP*128);

    if (FIRST) {
        // ---- encoder prologue: layer1 (VALU) -> hilo, layer2 (MFMA) -> hg ----
        float* w1s = (float*)arena;            // [4][64]
        float* b1v = (float*)(arena + 1024);   // [64]
        float* b2v = (float*)(arena + 1280);   // [64]
        w1s[t] = we1[t];
        if (t < 64) { b1v[t] = be1[t]; b2v[t] = be2[t]; }
        if (t < 128) out_batch[(size_t)g*128 + t] = (float)g;
        __syncthreads();

        const int n = t & 127, fh = t >> 7, f0 = fh*32;
        const float4 xv = ((const float4*)x)[g*128 + n];
        float acc1[32];
        #pragma unroll
        for (int q = 0; q < 8; ++q) {
            const float4 b4 = *(const float4*)(b1v + f0 + q*4);
            acc1[q*4+0] = b4.x; acc1[q*4+1] = b4.y; acc1[q*4+2] = b4.z; acc1[q*4+3] = b4.w;
        }
        #pragma unroll
        for (int k = 0; k < 4; ++k) {
            const float xk = (k == 0) ? xv.x : (k == 1) ? xv.y : (k == 2) ? xv.z : xv.w;
            #pragma unroll
            for (int q = 0; q < 8; ++q) {
                const float4 w4 = *(const float4*)(w1s + k*64 + f0 + q*4);   // broadcast
                acc1[q*4+0] = fmaf(xk, w4.x, acc1[q*4+0]);
                acc1[q*4+1] = fmaf(xk, w4.y, acc1[q*4+1]);
                acc1[q*4+2] = fmaf(xk, w4.z, acc1[q*4+2]);
                acc1[q*4+3] = fmaf(xk, w4.w, acc1[q*4+3]);
            }
        }
        unsigned hiw[16], low[16];
        #pragma unroll
        for (int q = 0; q < 16; ++q) {
            const float v0 = elu_f(acc1[2*q]), v1 = elu_f(acc1[2*q+1]);
            unsigned short h0, l0, h1, l1;
            split_bf16(v0, h0, l0); split_bf16(v1, h1, l1);
            hiw[q] = (unsigned)h0 | ((unsigned)h1 << 16);
            low[q] = (unsigned)l0 | ((unsigned)l1 << 16);
        }
        uint4* dh = (uint4*)(hilo + n*136 + f0);
        uint4* dl = (uint4*)(hilo + n*136 + 64 + f0);
        #pragma unroll
        for (int q = 0; q < 4; ++q) {
            dh[q] = make_uint4(hiw[q*4], hiw[q*4+1], hiw[q*4+2], hiw[q*4+3]);
            dl[q] = make_uint4(low[q*4], low[q*4+1], low[q*4+2], low[q*4+3]);
        }
        __syncthreads();

        // layer2 via MFMA: h2 = elu(h1 @ we2 + be2) -> hg
        #pragma unroll 1
        for (int jt = 0; jt < 2; ++jt) {
            floatx16 acc = {0.f,0.f,0.f,0.f,0.f,0.f,0.f,0.f,0.f,0.f,0.f,0.f,0.f,0.f,0.f,0.f};
            #pragma unroll
            for (int p = 0; p < 3; ++p) {
                const int Asel = (p == 2) ? 64 : 0;
                const int part = (p == 1) ? 1 : 0;
                #pragma unroll
                for (int c = 0; c < 4; ++c) {
                    const short8 af = *(const short8*)(hilo + (w*32 + lj)*136 + Asel + c*16 + half*8);
                    const short8 bf = *(const short8*)((const short*)we2p + part*4096 + (((c*2 + half)*64) + jt*32 + lj)*8);
                    acc = __builtin_amdgcn_mfma_f32_32x32x16_bf16(af, bf, acc, 0, 0, 0);
                }
            }
            const int col = jt*32 + lj;
            const float bias = b2v[col];
            #pragma unroll
            for (int reg = 0; reg < 16; ++reg) {
                const int row = (reg & 3) + 8*(reg >> 2) + 4*half + w*32;
                hg[(size_t)row*64 + col] = elu_f(acc[reg] + bias);
            }
        }
        __syncthreads();
    }

    // ---- phase 0: stage h -> hi/lo bf16 + sq ----
    {
        const int r = t >> 1, c0 = (t & 1) * 32;
        const float4* src = (const float4*)(hg + r*64 + c0);
        unsigned hh[16], llo[16];
        float s = 0.0f;
        #pragma unroll
        for (int q = 0; q < 8; ++q) {
            const float4 v = src[q];
            s = fmaf(v.x, v.x, s); s = fmaf(v.y, v.y, s);
            s = fmaf(v.z, v.z, s); s = fmaf(v.w, v.w, s);
            unsigned short hx, lx, hy, ly, hz, lz, hw2, lw2;
            split_bf16(v.x, hx, lx); split_bf16(v.y, hy, ly);
            split_bf16(v.z, hz, lz); split_bf16(v.w, hw2, lw2);
            hh[q*2]   = (unsigned)hx | ((unsigned)hy << 16);
            hh[q*2+1] = (unsigned)hz | ((unsigned)hw2 << 16);
            llo[q*2]   = (unsigned)lx | ((unsigned)ly << 16);
            llo[q*2+1] = (unsigned)lz | ((unsigned)lw2 << 16);
        }
        uint4* dh = (uint4*)(hilo + r*136 + c0);
        uint4* dl = (uint4*)(hilo + r*136 + 64 + c0);
        #pragma unroll
        for (int q = 0; q < 4; ++q) {
            dh[q] = make_uint4(hh[q*4], hh[q*4+1], hh[q*4+2], hh[q*4+3]);
            dl[q] = make_uint4(llo[q*4], llo[q*4+1], llo[q*4+2], llo[q*4+3]);
        }
        s += __shfl_xor(s, 1);
        if ((t & 1) == 0) sqs[r] = s;
    }
    __syncthreads();

    // ---- phase 2: ab-GEMM via MFMA: out = hiLo @ Wpack (+bc on a-cols), write to global ab ----
    #pragma unroll 1
    for (int jt = 0; jt < 4; ++jt) {
        floatx16 acc = {0.f,0.f,0.f,0.f,0.f,0.f,0.f,0.f,0.f,0.f,0.f,0.f,0.f,0.f,0.f,0.f};
        #pragma unroll
        for (int p = 0; p < 3; ++p) {                 // (A,B): (hi,hi),(hi,lo),(lo,hi)
            const int Asel = (p == 2) ? 64 : 0;
            const int part = (p == 1) ? 1 : 0;
            #pragma unroll
            for (int c = 0; c < 4; ++c) {
                const short8 af = *(const short8*)(hilo + (w*32 + lj)*136 + Asel + c*16 + half*8);
                const short8 bf = *(const short8*)((const short*)wp + part*8192 + (((c*2 + half)*128) + jt*32 + lj)*8);
                acc = __builtin_amdgcn_mfma_f32_32x32x16_bf16(af, bf, acc, 0, 0, 0);
            }
        }
        const int col = jt*32 + lj;
        const float bias = (jt < 2) ? bc[col] : 0.0f;
        #pragma unroll
        for (int reg = 0; reg < 16; ++reg) {
            const int row = (reg & 3) + 8*(reg >> 2) + 4*half + w*32;
            abg[(size_t)row*128 + col] = acc[reg] + bias;
        }
    }

    // ---- phase 3: Gram strips via MFMA + per-strip top-k insertion ----
    unsigned bk[KNN];
    #pragma unroll
    for (int s = 0; s < KNN; ++s) bk[s] = 0xFFFFFFFFu;
    const int i2 = t & 127, jh = t >> 7;

    #pragma unroll 1
    for (int jt = 0; jt < 4; ++jt) {
        floatx16 acc = {0.f,0.f,0.f,0.f,0.f,0.f,0.f,0.f,0.f,0.f,0.f,0.f,0.f,0.f,0.f,0.f};
        #pragma unroll
        for (int p = 0; p < 3; ++p) {
            const int Asel = (p == 2) ? 64 : 0;
            const int Bsel = (p == 1) ? 64 : 0;
            #pragma unroll
            for (int c = 0; c < 4; ++c) {
                const short8 af = *(const short8*)(hilo + (w*32 + lj)*136 + Asel + c*16 + half*8);
                const short8 bf = *(const short8*)(hilo + (jt*32 + lj)*136 + Bsel + c*16 + half*8);
                acc = __builtin_amdgcn_mfma_f32_32x32x16_bf16(af, bf, acc, 0, 0, 0);
            }
        }
        const unsigned jg = (unsigned)(jt*32 + lj);
        const float sqj = sqs[jg];
        #pragma unroll
        for (int reg = 0; reg < 16; ++reg) {
            const int i = (reg & 3) + 8*(reg >> 2) + 4*half + w*32;
            float d = sqs[i] + sqj - 2.0f*acc[reg];
            d = fmaxf(d, 0.0f);
            keys[i*36 + lj] = (__float_as_uint(d) & 0xFFFFFF80u) | jg;
        }
        __syncthreads();
        const uint4* kp = (const uint4*)(keys + i2*36 + jh*16);
        #pragma unroll
        for (int c = 0; c < 4; ++c) {
            const uint4 kk = kp[c];
            const unsigned cand[4] = {kk.x, kk.y, kk.z, kk.w};
            #pragma unroll
            for (int e = 0; e < 4; ++e) {
                const unsigned key = cand[e];
                if (key < bk[KNN-1]) {
                    unsigned ck = key;
                    #pragma unroll
                    for (int s = 0; s < KNN; ++s) {
                        const unsigned os = bk[s];
                        const bool sw = ck < os;
                        bk[s] = sw ? ck : os;
                        ck   = sw ? os : ck;
                    }
                }
            }
        }
        __syncthreads();
    }

    // ---- phase 4: merge half-lists (hiLo dead -> mkey aliases it) ----
    unsigned* mkey = (unsigned*)(arena + 18432);   // [128][49]
    #pragma unroll
    for (int s = 0; s < KNN; ++s) mkey[i2*49 + jh*24 + s] = bk[s];
    __syncthreads();
    if (t < 128) {
        unsigned bm[KNN];
        #pragma unroll
        for (int s = 0; s < KNN; ++s) bm[s] = 0xFFFFFFFFu;
        #pragma unroll 1
        for (int c = 0; c < 2*KNN; ++c) {
            const unsigned key = mkey[t*49 + c];
            if (key < bm[KNN-1]) {
                unsigned ck = key;
                #pragma unroll
                for (int s = 0; s < KNN; ++s) {
                    const unsigned os = bm[s];
                    const bool sw = ck < os;
                    bm[s] = sw ? ck : os;
                    ck   = sw ? os : ck;
                }
            }
        }
        #pragma unroll
        for (int c = 0; c < 6; ++c) {
            nnw[t*6 + c] = (bm[c*4] & 127u) | ((bm[c*4+1] & 127u) << 8)
                         | ((bm[c*4+2] & 127u) << 16) | ((bm[c*4+3] & 127u) << 24);
        }
    }
    __syncthreads();

    // ---- phase 5: load b (ab cols 64..127) into LDS, aggregate out = elu(a + max_nn b) ----
    float* bs = (float*)(arena + 18432);           // [128][68]
    {
        const int r = t >> 1, c0 = (t & 1) * 32;
        const float4* bsrc = (const float4*)(abg + (size_t)r*128 + 64 + c0);
        float4* bdst = (float4*)(bs + r*68 + c0);
        #pragma unroll
        for (int q = 0; q < 8; ++q) bdst[q] = bsrc[q];
    }
    __syncthreads();
    {
        const int q = lane >> 4, fq = lane & 15;
        #pragma unroll 1
        for (int rg = 0; rg < 8; ++rg) {
            const int row = w*32 + rg*4 + q;
            float4 m = make_float4(-1e30f, -1e30f, -1e30f, -1e30f);
            #pragma unroll
            for (int c = 0; c < 6; ++c) {
                const unsigned pk = nnw[row*6 + c];
                #pragma unroll
                for (int e = 0; e < 4; ++e) {
                    const int j = (pk >> (8*e)) & 127;
                    const float4 v = *(const float4*)(bs + j*68 + fq*4);
                    m.x = fmaxf(m.x, v.x); m.y = fmaxf(m.y, v.y);
                    m.z = fmaxf(m.z, v.z); m.w = fmaxf(m.w, v.w);
                }
            }
            const float4 av = *(const float4*)(abg + (size_t)row*128 + fq*4);
            float4 o;
            o.x = elu_f(av.x + m.x); o.y = elu_f(av.y + m.y);
            o.z = elu_f(av.z + m.z); o.w = elu_f(av.w + m.w);
            *(float4*)(hg + (size_t)row*64 + fq*4) = o;
        }
    }
}

// ---------------- head: sum-pool over nodes + 5-layer MLP ----------------
__global__ __launch_bounds__(256) void head_kernel(
    const float* __restrict__ h,
    const float* __restrict__ wo1, const float* __restrict__ bo1,
    const float* __restrict__ wo2, const float* __restrict__ bo2,
    const float* __restrict__ wo3, const float* __restrict__ bo3,
    const float* __restrict__ wo4, const float* __restrict__ bo4,
    const float* __restrict__ wo5, const float* __restrict__ bo5,
    float* __restrict__ outp)
{
    __shared__ float pool4[4][64];
    __shared__ float pooled[64];
    __shared__ float o1[64];
    __shared__ float o2[32];
    __shared__ float o3[32];
    __shared__ float o4[8];
    const int g = blockIdx.x, t = threadIdx.x;
    const int f = t & 63, q = t >> 6;
    const float* __restrict__ hg = h + (size_t)g * (NP*HID);

    float s = 0.0f;
    #pragma unroll 8
    for (int n = q; n < NP; n += 4) s += hg[n*64 + f];
    pool4[q][f] = s;
    __syncthreads();

    if (t < 64) {
        pooled[t] = pool4[0][t] + pool4[1][t] + pool4[2][t] + pool4[3][t];
        {
            float acc = bo1[t];
            #pragma unroll
            for (int k = 0; k < 64; ++k) acc = fmaf(pooled[k], wo1[k*64 + t], acc);
            o1[t] = elu_f(acc);
        }
        if (t < 32) {
            float acc = bo2[t];
            #pragma unroll
            for (int k = 0; k < 64; ++k) acc = fmaf(o1[k], wo2[k*32 + t], acc);
            o2[t] = elu_f(acc);
        }
        if (t < 32) {
            float acc = bo3[t];
            #pragma unroll
            for (int k = 0; k < 32; ++k) acc = fmaf(o2[k], wo3[k*32 + t], acc);
            o3[t] = elu_f(acc);
        }
        if (t < 8) {
            float acc = bo4[t];
            #pragma unroll
            for (int k = 0; k < 32; ++k) acc = fmaf(o3[k], wo4[k*8 + t], acc);
            o4[t] = elu_f(acc);
        }
        if (t == 0) {
            float acc = bo5[0];
            #pragma unroll
            for (int k = 0; k < 8; ++k) acc = fmaf(o4[k], wo5[k], acc);
            outp[g] = acc;
        }
    }
}

extern "C" void kernel_launch(void* const* d_in, const int* in_sizes, int n_in,
                              void* d_out, int out_size, void* d_ws, size_t ws_size,
                              hipStream_t stream) {
    const float* x_pf = (const float*)d_in[0];
    const float* we1 = (const float*)d_in[2];
    const float* be1 = (const float*)d_in[3];
    const float* we2 = (const float*)d_in[4];
    const float* be2 = (const float*)d_in[5];
    const float* wc1 = (const float*)d_in[6];
    const float* bc1 = (const float*)d_in[7];
    const float* wc2 = (const float*)d_in[8];
    const float* bc2 = (const float*)d_in[9];
    const float* wc3 = (const float*)d_in[10];
    const float* bc3 = (const float*)d_in[11];
    const float* wo1 = (const float*)d_in[12];
    const float* bo1 = (const float*)d_in[13];
    const float* wo2 = (const float*)d_in[14];
    const float* bo2 = (const float*)d_in[15];
    const float* wo3 = (const float*)d_in[16];
    const float* bo3 = (const float*)d_in[17];
    const float* wo4 = (const float*)d_in[18];
    const float* bo4 = (const float*)d_in[19];
    const float* wo5 = (const float*)d_in[20];
    const float* bo5 = (const float*)d_in[21];

    float* out = (float*)d_out;           // [0:512) outputs, [512:) batch ids (as float)
    char* ws = (char*)d_ws;
    float* h0 = (float*)(ws);                                    // 16 MB
    float* ab = (float*)(ws + (size_t)16*1024*1024);             // 32 MB
    unsigned short* wpack = (unsigned short*)(ws + (size_t)48*1024*1024);  // 112 KB

    pack_w<<<112, 256, 0, stream>>>(wc1, wc2, wc3, we2, wpack);

    conv_fused<true><<<NG, 256, 0, stream>>>(h0, wpack, bc1, ab,
        x_pf, we1, be1, wpack + 49152, be2, out + NG);
    conv_fused<false><<<NG, 256, 0, stream>>>(h0, wpack + 16384, bc2, ab,
        nullptr, nullptr, nullptr, nullptr, nullptr, nullptr);
    conv_fused<false><<<NG, 256, 0, stream>>>(h0, wpack + 32768, bc3, ab,
        nullptr, nullptr, nullptr, nullptr, nullptr, nullptr);

    head_kernel<<<NG, 256, 0, stream>>>(h0, wo1, bo1, wo2, bo2, wo3, bo3, wo4, bo4, wo5, bo5, out);
}

// Round 5
// 207.050 us; speedup vs baseline: 4.5645x; 1.2801x over previous
//
#include <hip/hip_runtime.h>
#include <math.h>

#define NG 512
#define NP 128
#define HID 64
#define KNN 24
#define NTOT (NG*NP)

typedef __attribute__((ext_vector_type(8)))  short  short8;
typedef __attribute__((ext_vector_type(16))) float  floatx16;

__device__ __forceinline__ float elu_f(float v) { return v > 0.0f ? v : expm1f(v); }

__device__ __forceinline__ void split_bf16(float x, unsigned short& hb, unsigned short& lb) {
    unsigned u = __float_as_uint(x);
    unsigned h = (u + 0x7FFFu + ((u >> 16) & 1u)) >> 16;
    hb = (unsigned short)h;
    float hf = __uint_as_float(h << 16);
    float lo = x - hf;
    unsigned v = __float_as_uint(lo);
    lb = (unsigned short)((v + 0x7FFFu + ((v >> 16) & 1u)) >> 16);
}

// XOR-swizzled hilo accessor: row has 16 chunks of 16B (hi = 0..7, lo = 8..15).
// phys chunk = ch ^ (row & 15); stride 64 words/row => conflict-free frag reads.
__device__ __forceinline__ unsigned short* hchunk(unsigned short* base, int row, int ch) {
    return base + (((row << 4) + (ch ^ (row & 15))) << 3);
}
__device__ __forceinline__ const unsigned short* hchunk(const unsigned short* base, int row, int ch) {
    return base + (((row << 4) + (ch ^ (row & 15))) << 3);
}

// bitonic sort 8 ascending (fully unrolled -> min/max network)
__device__ __forceinline__ void sort8_asc(unsigned* y) {
    #pragma unroll
    for (int k = 2; k <= 8; k <<= 1)
        #pragma unroll
        for (int j = k >> 1; j > 0; j >>= 1)
            #pragma unroll
            for (int i = 0; i < 8; ++i) {
                const int l = i ^ j;
                if (l > i) {
                    const bool up = ((i & k) == 0);
                    const unsigned a = y[i], b = y[l];
                    const unsigned mn = a < b ? a : b;
                    const unsigned mx = a < b ? b : a;
                    y[i] = up ? mn : mx;
                    y[l] = up ? mx : mn;
                }
            }
}

// x[0..23] sorted asc, x[24..31] sorted DESC => x[0..31] bitonic.
// Bitonic merge keeping smallest 24 sorted (CEs fully inside [24..31] pruned).
__device__ __forceinline__ void merge_top24(unsigned* x) {
    #pragma unroll
    for (int d = 16; d > 0; d >>= 1)
        #pragma unroll
        for (int i = 0; i < 32; ++i)
            if (!(i & d) && i < 24) {
                const int l = i | d;
                const unsigned a = x[i], b = x[l];
                x[i] = a < b ? a : b;
                x[l] = a < b ? b : a;
            }
}

// ---------------- pack weights into MFMA-B-fragment-ready hi/lo bf16 layout ----------------
__global__ __launch_bounds__(256) void pack_w(
    const float* __restrict__ wc1, const float* __restrict__ wc2, const float* __restrict__ wc3,
    const float* __restrict__ we2,
    unsigned short* __restrict__ wp)
{
    const int n = blockIdx.x*256 + threadIdx.x;      // 0..28671
    if (n < 24576) {
        const int layer = n >> 13;
        const int r = n & 8191;
        const int e = r & 7, j = (r >> 3) & 127, ch = r >> 10;
        const int k = (ch >> 1)*16 + (ch & 1)*8 + e;
        const float* wc = (layer == 0) ? wc1 : ((layer == 1) ? wc2 : wc3);
        float w;
        if (j < 64) w = wc[k*64 + j] - wc[(k+64)*64 + j];
        else        w = wc[(k+64)*64 + (j-64)];
        unsigned short hb, lb;
        split_bf16(w, hb, lb);
        unsigned short* base = wp + layer*16384;
        base[r] = hb;
        base[8192 + r] = lb;
    } else if (n < 24576 + 4096) {
        const int m = n - 24576;                      // 0..4095
        const int e = m & 7, col = (m >> 3) & 63, ch = m >> 9;
        const int k = (ch >> 1)*16 + (ch & 1)*8 + e;
        unsigned short hb, lb;
        split_bf16(we2[k*64 + col], hb, lb);
        unsigned short* base = wp + 49152;
        base[m] = hb;
        base[4096 + m] = lb;
    }
}

// ---------------- fused conv (+optional encoder) ----------------
// Arena: keys[128][36] u32 @0 (18432; FIRST prologue w-staging aliases; nnw packed into cols 30..35)
//        | hilo (swizzled, 128 rows x 16 chunks x 16B) @18432 (32768; bs[128][64] f32 aliases in phase ab)
//        | sq[128] f32 @51200.  Total 51712 B -> 3 blocks/CU.
template <bool FIRST>
__global__ __launch_bounds__(256, 3) void conv_fused(
    float* __restrict__ h,                       // in/out [512][128][64]
    const unsigned short* __restrict__ wp,       // this layer's packed conv weights
    const float* __restrict__ bc,
    float* __restrict__ ag_all,                  // scratch [512][128][64] for a
    const float* __restrict__ x,                 // FIRST only
    const float* __restrict__ we1, const float* __restrict__ be1,
    const unsigned short* __restrict__ we2p,     // FIRST only
    const float* __restrict__ be2,
    float* __restrict__ out_batch)               // FIRST only
{
    __shared__ __align__(16) char arena[51712];
    unsigned*        keys = (unsigned*)arena;
    unsigned short*  hilo = (unsigned short*)(arena + 18432);
    float*           sqs  = (float*)(arena + 51200);

    const int g = blockIdx.x;
    const int t = threadIdx.x;
    const int lane = t & 63, w = t >> 6;
    const int lj = lane & 31, half = lane >> 5;
    const int i2 = t & 127, jh = t >> 7;
    float* __restrict__ hg = h + (size_t)g * (NP*HID);
    float* __restrict__ ag = ag_all + (size_t)g * (NP*HID);

    if (FIRST) {
        // encoder prologue: layer1 (VALU, broadcast weights) -> hilo, layer2 (MFMA) -> hg
        float* w1s = (float*)arena;            // [4][64]
        float* b1v = (float*)(arena + 1024);   // [64]
        float* b2v = (float*)(arena + 1280);   // [64]
        w1s[t] = we1[t];
        if (t < 64) { b1v[t] = be1[t]; b2v[t] = be2[t]; }
        if (t < 128) out_batch[(size_t)g*128 + t] = (float)g;
        __syncthreads();

        const int n = t & 127, fh = t >> 7, f0 = fh*32;
        const float4 xv = ((const float4*)x)[g*128 + n];
        float acc1[32];
        #pragma unroll
        for (int q = 0; q < 8; ++q) {
            const float4 b4 = *(const float4*)(b1v + f0 + q*4);
            acc1[q*4+0] = b4.x; acc1[q*4+1] = b4.y; acc1[q*4+2] = b4.z; acc1[q*4+3] = b4.w;
        }
        #pragma unroll
        for (int k = 0; k < 4; ++k) {
            const float xk = (k == 0) ? xv.x : (k == 1) ? xv.y : (k == 2) ? xv.z : xv.w;
            #pragma unroll
            for (int q = 0; q < 8; ++q) {
                const float4 w4 = *(const float4*)(w1s + k*64 + f0 + q*4);
                acc1[q*4+0] = fmaf(xk, w4.x, acc1[q*4+0]);
                acc1[q*4+1] = fmaf(xk, w4.y, acc1[q*4+1]);
                acc1[q*4+2] = fmaf(xk, w4.z, acc1[q*4+2]);
                acc1[q*4+3] = fmaf(xk, w4.w, acc1[q*4+3]);
            }
        }
        unsigned hiw[16], low[16];
        #pragma unroll
        for (int q = 0; q < 16; ++q) {
            const float v0 = elu_f(acc1[2*q]), v1 = elu_f(acc1[2*q+1]);
            unsigned short h0, l0, h1, l1;
            split_bf16(v0, h0, l0); split_bf16(v1, h1, l1);
            hiw[q] = (unsigned)h0 | ((unsigned)h1 << 16);
            low[q] = (unsigned)l0 | ((unsigned)l1 << 16);
        }
        #pragma unroll
        for (int q = 0; q < 4; ++q) {
            *(uint4*)hchunk(hilo, n, fh*4 + q)     = make_uint4(hiw[q*4], hiw[q*4+1], hiw[q*4+2], hiw[q*4+3]);
            *(uint4*)hchunk(hilo, n, 8 + fh*4 + q) = make_uint4(low[q*4], low[q*4+1], low[q*4+2], low[q*4+3]);
        }
        __syncthreads();

        #pragma unroll 1
        for (int jt = 0; jt < 2; ++jt) {
            short8 afr[8], bfr[8];
            #pragma unroll
            for (int sel = 0; sel < 2; ++sel)
                #pragma unroll
                for (int c = 0; c < 4; ++c) {
                    afr[sel*4+c] = *(const short8*)hchunk(hilo, w*32 + lj, sel*8 + c*2 + half);
                    bfr[sel*4+c] = *(const short8*)((const short*)we2p + sel*4096 + (((c*2 + half)*64) + jt*32 + lj)*8);
                }
            floatx16 acc = {0.f,0.f,0.f,0.f,0.f,0.f,0.f,0.f,0.f,0.f,0.f,0.f,0.f,0.f,0.f,0.f};
            #pragma unroll
            for (int c = 0; c < 4; ++c) acc = __builtin_amdgcn_mfma_f32_32x32x16_bf16(afr[c],   bfr[c],   acc, 0, 0, 0);
            #pragma unroll
            for (int c = 0; c < 4; ++c) acc = __builtin_amdgcn_mfma_f32_32x32x16_bf16(afr[c],   bfr[4+c], acc, 0, 0, 0);
            #pragma unroll
            for (int c = 0; c < 4; ++c) acc = __builtin_amdgcn_mfma_f32_32x32x16_bf16(afr[4+c], bfr[c],   acc, 0, 0, 0);
            const int col = jt*32 + lj;
            const float bias = b2v[col];
            #pragma unroll
            for (int reg = 0; reg < 16; ++reg) {
                const int row = (reg & 3) + 8*(reg >> 2) + 4*half + w*32;
                hg[(size_t)row*64 + col] = elu_f(acc[reg] + bias);
            }
        }
        __syncthreads();
    }

    // ---- phase 0: stage h -> swizzled hi/lo bf16 + sq ----
    {
        const int r = t >> 1, cb = (t & 1) * 4;
        const float4* src = (const float4*)(hg + r*64 + cb*8);
        unsigned hh[16], llo[16];
        float s = 0.0f;
        #pragma unroll
        for (int q = 0; q < 8; ++q) {
            const float4 v = src[q];
            s = fmaf(v.x, v.x, s); s = fmaf(v.y, v.y, s);
            s = fmaf(v.z, v.z, s); s = fmaf(v.w, v.w, s);
            unsigned short hx, lx, hy, ly, hz, lz, hw2, lw2;
            split_bf16(v.x, hx, lx); split_bf16(v.y, hy, ly);
            split_bf16(v.z, hz, lz); split_bf16(v.w, hw2, lw2);
            hh[q*2]   = (unsigned)hx | ((unsigned)hy << 16);
            hh[q*2+1] = (unsigned)hz | ((unsigned)hw2 << 16);
            llo[q*2]   = (unsigned)lx | ((unsigned)ly << 16);
            llo[q*2+1] = (unsigned)lz | ((unsigned)lw2 << 16);
        }
        #pragma unroll
        for (int q = 0; q < 4; ++q) {
            *(uint4*)hchunk(hilo, r, cb + q)     = make_uint4(hh[q*4], hh[q*4+1], hh[q*4+2], hh[q*4+3]);
            *(uint4*)hchunk(hilo, r, 8 + cb + q) = make_uint4(llo[q*4], llo[q*4+1], llo[q*4+2], llo[q*4+3]);
        }
        s += __shfl_xor(s, 1);
        if ((t & 1) == 0) sqs[r] = s;
    }
    __syncthreads();

    // ---- Gram strips (MFMA) + batched-bitonic top-k ----
    unsigned xk[32];
    #pragma unroll
    for (int s = 0; s < 24; ++s) xk[s] = 0xFFFFFFFFu;

    #pragma unroll 1
    for (int jt = 0; jt < 4; ++jt) {
        short8 afr[8], bfr[8];
        #pragma unroll
        for (int sel = 0; sel < 2; ++sel)
            #pragma unroll
            for (int c = 0; c < 4; ++c) {
                afr[sel*4+c] = *(const short8*)hchunk(hilo, w*32 + lj,  sel*8 + c*2 + half);
                bfr[sel*4+c] = *(const short8*)hchunk(hilo, jt*32 + lj, sel*8 + c*2 + half);
            }
        floatx16 acc = {0.f,0.f,0.f,0.f,0.f,0.f,0.f,0.f,0.f,0.f,0.f,0.f,0.f,0.f,0.f,0.f};
        #pragma unroll
        for (int c = 0; c < 4; ++c) acc = __builtin_amdgcn_mfma_f32_32x32x16_bf16(afr[c],   bfr[c],   acc, 0, 0, 0);
        #pragma unroll
        for (int c = 0; c < 4; ++c) acc = __builtin_amdgcn_mfma_f32_32x32x16_bf16(afr[c],   bfr[4+c], acc, 0, 0, 0);
        #pragma unroll
        for (int c = 0; c < 4; ++c) acc = __builtin_amdgcn_mfma_f32_32x32x16_bf16(afr[4+c], bfr[c],   acc, 0, 0, 0);

        const unsigned jg = (unsigned)(jt*32 + lj);
        const float sqj = sqs[jg];
        #pragma unroll
        for (int reg = 0; reg < 16; ++reg) {
            const int i = (reg & 3) + 8*(reg >> 2) + 4*half + w*32;
            float d = fmaf(-2.0f, acc[reg], sqs[i] + sqj);
            d = fmaxf(d, 0.0f);
            keys[i*36 + lj] = (__float_as_uint(d) & 0xFFFFFF80u) | jg;
        }
        __syncthreads();

        const unsigned* kr = keys + i2*36 + jh*16;
        #pragma unroll
        for (int b = 0; b < 2; ++b) {
            const uint4 k0 = *(const uint4*)(kr + b*8);
            const uint4 k1 = *(const uint4*)(kr + b*8 + 4);
            unsigned y[8] = {k0.x, k0.y, k0.z, k0.w, k1.x, k1.y, k1.z, k1.w};
            sort8_asc(y);
            #pragma unroll
            for (int e = 0; e < 8; ++e) xk[24+e] = y[7-e];
            merge_top24(xk);
        }
        __syncthreads();
    }

    // ---- merge half-lists, pack nnidx into keys cols 30..35 ----
    if (jh) {
        #pragma unroll
        for (int s = 0; s < 24; ++s) keys[i2*36 + s] = xk[s];
    }
    __syncthreads();
    if (!jh) {
        #pragma unroll
        for (int b = 0; b < 3; ++b) {
            #pragma unroll
            for (int e = 0; e < 8; ++e) xk[24+e] = keys[i2*36 + b*8 + (7-e)];
            merge_top24(xk);
        }
        #pragma unroll
        for (int c = 0; c < 6; ++c)
            keys[i2*36 + 30 + c] = (xk[c*4] & 127u) | ((xk[c*4+1] & 127u) << 8)
                                 | ((xk[c*4+2] & 127u) << 16) | ((xk[c*4+3] & 127u) << 24);
    }
    __syncthreads();

    // ---- ab-GEMM (MFMA): a -> global (+bias), b -> LDS bs (aliases dead hilo) ----
    float* bs = (float*)(arena + 18432);   // [128][64]
    {
        short8 afr[8];
        #pragma unroll
        for (int sel = 0; sel < 2; ++sel)
            #pragma unroll
            for (int c = 0; c < 4; ++c)
                afr[sel*4+c] = *(const short8*)hchunk(hilo, w*32 + lj, sel*8 + c*2 + half);
        __syncthreads();   // all hilo reads done before bs overwrites

        #pragma unroll 1
        for (int jt = 0; jt < 4; ++jt) {
            short8 bfr[8];
            #pragma unroll
            for (int part = 0; part < 2; ++part)
                #pragma unroll
                for (int c = 0; c < 4; ++c)
                    bfr[part*4+c] = *(const short8*)((const short*)wp + part*8192 + (((c*2 + half)*128) + jt*32 + lj)*8);
            floatx16 acc = {0.f,0.f,0.f,0.f,0.f,0.f,0.f,0.f,0.f,0.f,0.f,0.f,0.f,0.f,0.f,0.f};
            #pragma unroll
            for (int c = 0; c < 4; ++c) acc = __builtin_amdgcn_mfma_f32_32x32x16_bf16(afr[c],   bfr[c],   acc, 0, 0, 0);
            #pragma unroll
            for (int c = 0; c < 4; ++c) acc = __builtin_amdgcn_mfma_f32_32x32x16_bf16(afr[c],   bfr[4+c], acc, 0, 0, 0);
            #pragma unroll
            for (int c = 0; c < 4; ++c) acc = __builtin_amdgcn_mfma_f32_32x32x16_bf16(afr[4+c], bfr[c],   acc, 0, 0, 0);

            if (jt < 2) {
                const int col = jt*32 + lj;
                const float bias = bc[col];
                #pragma unroll
                for (int reg = 0; reg < 16; ++reg) {
                    const int row = (reg & 3) + 8*(reg >> 2) + 4*half + w*32;
                    ag[(size_t)row*64 + col] = acc[reg] + bias;
                }
            } else {
                const int colb = (jt - 2)*32 + lj;
                #pragma unroll
                for (int reg = 0; reg < 16; ++reg) {
                    const int row = (reg & 3) + 8*(reg >> 2) + 4*half + w*32;
                    bs[row*64 + colb] = acc[reg];
                }
            }
        }
    }
    __syncthreads();

    // ---- aggregation: out = elu(a + max_nn b) ----
    {
        const int q = lane >> 4, fq = lane & 15;
        float4 av[8];
        #pragma unroll
        for (int rg = 0; rg < 8; ++rg)
            av[rg] = *(const float4*)(ag + (size_t)(w*32 + rg*4 + q)*64 + fq*4);
        #pragma unroll 1
        for (int rg = 0; rg < 8; ++rg) {
            const int row = w*32 + rg*4 + q;
            float4 m = make_float4(-1e30f, -1e30f, -1e30f, -1e30f);
            #pragma unroll
            for (int c = 0; c < 6; ++c) {
                const unsigned pk = keys[row*36 + 30 + c];
                #pragma unroll
                for (int e = 0; e < 4; ++e) {
                    const int j = (pk >> (8*e)) & 127;
                    const float4 v = *(const float4*)(bs + j*64 + fq*4);
                    m.x = fmaxf(m.x, v.x); m.y = fmaxf(m.y, v.y);
                    m.z = fmaxf(m.z, v.z); m.w = fmaxf(m.w, v.w);
                }
            }
            float4 o;
            o.x = elu_f(av[rg].x + m.x); o.y = elu_f(av[rg].y + m.y);
            o.z = elu_f(av[rg].z + m.z); o.w = elu_f(av[rg].w + m.w);
            *(float4*)(hg + (size_t)row*64 + fq*4) = o;
        }
    }
}

// ---------------- head: sum-pool over nodes + 5-layer MLP ----------------
__global__ __launch_bounds__(256) void head_kernel(
    const float* __restrict__ h,
    const float* __restrict__ wo1, const float* __restrict__ bo1,
    const float* __restrict__ wo2, const float* __restrict__ bo2,
    const float* __restrict__ wo3, const float* __restrict__ bo3,
    const float* __restrict__ wo4, const float* __restrict__ bo4,
    const float* __restrict__ wo5, const float* __restrict__ bo5,
    float* __restrict__ outp)
{
    __shared__ float pool4[4][64];
    __shared__ float pooled[64];
    __shared__ float o1[64];
    __shared__ float o2[32];
    __shared__ float o3[32];
    __shared__ float o4[8];
    const int g = blockIdx.x, t = threadIdx.x;
    const int f = t & 63, q = t >> 6;
    const float* __restrict__ hg = h + (size_t)g * (NP*HID);

    float s = 0.0f;
    #pragma unroll 8
    for (int n = q; n < NP; n += 4) s += hg[n*64 + f];
    pool4[q][f] = s;
    __syncthreads();

    if (t < 64) {
        pooled[t] = pool4[0][t] + pool4[1][t] + pool4[2][t] + pool4[3][t];
        {
            float acc = bo1[t];
            #pragma unroll
            for (int k = 0; k < 64; ++k) acc = fmaf(pooled[k], wo1[k*64 + t], acc);
            o1[t] = elu_f(acc);
        }
        if (t < 32) {
            float acc = bo2[t];
            #pragma unroll
            for (int k = 0; k < 64; ++k) acc = fmaf(o1[k], wo2[k*32 + t], acc);
            o2[t] = elu_f(acc);
        }
        if (t < 32) {
            float acc = bo3[t];
            #pragma unroll
            for (int k = 0; k < 32; ++k) acc = fmaf(o2[k], wo3[k*32 + t], acc);
            o3[t] = elu_f(acc);
        }
        if (t < 8) {
            float acc = bo4[t];
            #pragma unroll
            for (int k = 0; k < 32; ++k) acc = fmaf(o3[k], wo4[k*8 + t], acc);
            o4[t] = elu_f(acc);
        }
        if (t == 0) {
            float acc = bo5[0];
            #pragma unroll
            for (int k = 0; k < 8; ++k) acc = fmaf(o4[k], wo5[k], acc);
            outp[g] = acc;
        }
    }
}

extern "C" void kernel_launch(void* const* d_in, const int* in_sizes, int n_in,
                              void* d_out, int out_size, void* d_ws, size_t ws_size,
                              hipStream_t stream) {
    const float* x_pf = (const float*)d_in[0];
    const float* we1 = (const float*)d_in[2];
    const float* be1 = (const float*)d_in[3];
    const float* we2 = (const float*)d_in[4];
    const float* be2 = (const float*)d_in[5];
    const float* wc1 = (const float*)d_in[6];
    const float* bc1 = (const float*)d_in[7];
    const float* wc2 = (const float*)d_in[8];
    const float* bc2 = (const float*)d_in[9];
    const float* wc3 = (const float*)d_in[10];
    const float* bc3 = (const float*)d_in[11];
    const float* wo1 = (const float*)d_in[12];
    const float* bo1 = (const float*)d_in[13];
    const float* wo2 = (const float*)d_in[14];
    const float* bo2 = (const float*)d_in[15];
    const float* wo3 = (const float*)d_in[16];
    const float* bo3 = (const float*)d_in[17];
    const float* wo4 = (const float*)d_in[18];
    const float* bo4 = (const float*)d_in[19];
    const float* wo5 = (const float*)d_in[20];
    const float* bo5 = (const float*)d_in[21];

    float* out = (float*)d_out;           // [0:512) outputs, [512:) batch ids (as float)
    char* ws = (char*)d_ws;
    float* h0 = (float*)(ws);                                    // 16 MB
    float* abuf = (float*)(ws + (size_t)16*1024*1024);           // 16 MB
    unsigned short* wpack = (unsigned short*)(ws + (size_t)32*1024*1024);  // 112 KB

    pack_w<<<112, 256, 0, stream>>>(wc1, wc2, wc3, we2, wpack);

    conv_fused<true><<<NG, 256, 0, stream>>>(h0, wpack, bc1, abuf,
        x_pf, we1, be1, wpack + 49152, be2, out + NG);
    conv_fused<false><<<NG, 256, 0, stream>>>(h0, wpack + 16384, bc2, abuf,
        nullptr, nullptr, nullptr, nullptr, nullptr, nullptr);
    conv_fused<false><<<NG, 256, 0, stream>>>(h0, wpack + 32768, bc3, abuf,
        nullptr, nullptr, nullptr, nullptr, nullptr, nullptr);

    head_kernel<<<NG, 256, 0, stream>>>(h0, wo1, bo1, wo2, bo2, wo3, bo3, wo4, bo4, wo5, bo5, out);
}

// Round 6
// 189.123 us; speedup vs baseline: 4.9971x; 1.0948x over previous
//
#include <hip/hip_runtime.h>
#include <math.h>

#define NG 512
#define NP 128
#define HID 64
#define KNN 24
#define NTOT (NG*NP)

typedef __attribute__((ext_vector_type(8)))  short  short8;
typedef __attribute__((ext_vector_type(16))) float  floatx16;

__device__ __forceinline__ float elu_f(float v) { return v > 0.0f ? v : expm1f(v); }

__device__ __forceinline__ void split_bf16(float x, unsigned short& hb, unsigned short& lb) {
    unsigned u = __float_as_uint(x);
    unsigned h = (u + 0x7FFFu + ((u >> 16) & 1u)) >> 16;
    hb = (unsigned short)h;
    float hf = __uint_as_float(h << 16);
    float lo = x - hf;
    unsigned v = __float_as_uint(lo);
    lb = (unsigned short)((v + 0x7FFFu + ((v >> 16) & 1u)) >> 16);
}
__device__ __forceinline__ unsigned short bf_rne(float x) {
    unsigned u = __float_as_uint(x);
    return (unsigned short)((u + 0x7FFFu + ((u >> 16) & 1u)) >> 16);
}
__device__ __forceinline__ float bf_lo(unsigned u) { return __uint_as_float(u << 16); }
__device__ __forceinline__ float bf_hi(unsigned u) { return __uint_as_float(u & 0xFFFF0000u); }

// XOR-swizzled hilo accessor: row = 16 chunks of 16B (hi ch 0..7, lo ch 8..15).
__device__ __forceinline__ unsigned short* hchunk(unsigned short* base, int row, int ch) {
    return base + (((row << 4) + (ch ^ (row & 15))) << 3);
}
__device__ __forceinline__ const unsigned short* hchunk(const unsigned short* base, int row, int ch) {
    return base + (((row << 4) + (ch ^ (row & 15))) << 3);
}

// bitonic sort 8 ascending
__device__ __forceinline__ void sort8_asc(unsigned* y) {
    #pragma unroll
    for (int k = 2; k <= 8; k <<= 1)
        #pragma unroll
        for (int j = k >> 1; j > 0; j >>= 1)
            #pragma unroll
            for (int i = 0; i < 8; ++i) {
                const int l = i ^ j;
                if (l > i) {
                    const bool up = ((i & k) == 0);
                    const unsigned a = y[i], b = y[l];
                    const unsigned mn = a < b ? a : b;
                    const unsigned mx = a < b ? b : a;
                    y[i] = up ? mn : mx;
                    y[l] = up ? mx : mn;
                }
            }
}

// x[0..23] asc ++ x[24..31] desc (bitonic) -> keep smallest 24 sorted
__device__ __forceinline__ void merge_top24(unsigned* x) {
    #pragma unroll
    for (int d = 16; d > 0; d >>= 1)
        #pragma unroll
        for (int i = 0; i < 32; ++i)
            if (!(i & d) && i < 24) {
                const int l = i | d;
                const unsigned a = x[i], b = x[l];
                x[i] = a < b ? a : b;
                x[l] = a < b ? b : a;
            }
}

// ---------------- pack weights into MFMA-B-fragment-ready hi/lo bf16 layout ----------------
__global__ __launch_bounds__(256) void pack_w(
    const float* __restrict__ wc1, const float* __restrict__ wc2, const float* __restrict__ wc3,
    const float* __restrict__ we2,
    unsigned short* __restrict__ wp)
{
    const int n = blockIdx.x*256 + threadIdx.x;      // 0..28671
    if (n < 24576) {
        const int layer = n >> 13;
        const int r = n & 8191;
        const int e = r & 7, j = (r >> 3) & 127, ch = r >> 10;
        const int k = (ch >> 1)*16 + (ch & 1)*8 + e;
        const float* wc = (layer == 0) ? wc1 : ((layer == 1) ? wc2 : wc3);
        float w;
        if (j < 64) w = wc[k*64 + j] - wc[(k+64)*64 + j];
        else        w = wc[(k+64)*64 + (j-64)];
        unsigned short hb, lb;
        split_bf16(w, hb, lb);
        unsigned short* base = wp + layer*16384;
        base[r] = hb;
        base[8192 + r] = lb;
    } else if (n < 24576 + 4096) {
        const int m = n - 24576;
        const int e = m & 7, col = (m >> 3) & 63, ch = m >> 9;
        const int k = (ch >> 1)*16 + (ch & 1)*8 + e;
        unsigned short hb, lb;
        split_bf16(we2[k*64 + col], hb, lb);
        unsigned short* base = wp + 49152;
        base[m] = hb;
        base[4096 + m] = lb;
    }
}

// ---------------- single fused kernel: encoder + 3 dynamic-edge-conv layers + pooling ----------------
// 512 threads (8 waves), one graph per block.
// Arena (54784 B static):
//   keys  [128][36] u32 @0      (18432; aliases: prologue w/bias staging, bs bf16[128][68] in ab/agg phase)
//   nnidx [128][6]  u32 @18432  ( 3072; aliases pool8[8][64] f32 in final epilogue)
//   hilo  swizzled bf16 @21504  (32768)
//   sqs   [128] f32 @54272      (  512)
__global__ __launch_bounds__(512, 4) void conv_all(
    const float* __restrict__ x,
    const unsigned short* __restrict__ wp,
    const float* __restrict__ bc1, const float* __restrict__ bc2, const float* __restrict__ bc3,
    const float* __restrict__ we1, const float* __restrict__ be1,
    const unsigned short* __restrict__ we2p, const float* __restrict__ be2,
    float* __restrict__ ag_all, float* __restrict__ pooled_out, float* __restrict__ out_batch)
{
    __shared__ __align__(16) char arena[54784];
    unsigned*        keys  = (unsigned*)arena;
    unsigned*        nnidx = (unsigned*)(arena + 18432);
    unsigned short*  hilo  = (unsigned short*)(arena + 21504);
    float*           sqs   = (float*)(arena + 54272);

    const int g = blockIdx.x;
    const int t = threadIdx.x;
    const int w = t >> 6, lane = t & 63;
    const int lj = lane & 31, half = lane >> 5;
    const int rt = w & 3, wg = w >> 2;
    const int i2 = t & 127, s4 = t >> 7;
    float* __restrict__ ag = ag_all + (size_t)g * (NP*HID);

    // ================= encoder prologue =================
    {
        float* w1s = (float*)arena;            // [4][64]
        float* b1v = (float*)(arena + 1024);   // [64]
        float* b2v = (float*)(arena + 1280);   // [64]
        if (t < 256) w1s[t] = we1[t];
        else if (t < 320) b1v[t-256] = be1[t-256];
        else if (t < 384) b2v[t-320] = be2[t-320];
        if (t < 128) out_batch[(size_t)g*128 + t] = (float)g;
        __syncthreads();

        // layer 1: n = node, fh = col-quarter (16 cols)
        const int n = t & 127, fh = t >> 7, f0 = fh*16;
        const float4 xv = ((const float4*)x)[g*128 + n];
        float acc1[16];
        #pragma unroll
        for (int q = 0; q < 4; ++q) {
            const float4 b4 = *(const float4*)(b1v + f0 + q*4);
            acc1[q*4+0] = b4.x; acc1[q*4+1] = b4.y; acc1[q*4+2] = b4.z; acc1[q*4+3] = b4.w;
        }
        #pragma unroll
        for (int k = 0; k < 4; ++k) {
            const float xk_ = (k == 0) ? xv.x : (k == 1) ? xv.y : (k == 2) ? xv.z : xv.w;
            #pragma unroll
            for (int q = 0; q < 4; ++q) {
                const float4 w4 = *(const float4*)(w1s + k*64 + f0 + q*4);
                acc1[q*4+0] = fmaf(xk_, w4.x, acc1[q*4+0]);
                acc1[q*4+1] = fmaf(xk_, w4.y, acc1[q*4+1]);
                acc1[q*4+2] = fmaf(xk_, w4.z, acc1[q*4+2]);
                acc1[q*4+3] = fmaf(xk_, w4.w, acc1[q*4+3]);
            }
        }
        unsigned hu[8], lu[8];
        #pragma unroll
        for (int e = 0; e < 8; ++e) {
            const float v0 = elu_f(acc1[2*e]), v1 = elu_f(acc1[2*e+1]);
            unsigned short h0, l0, h1, l1;
            split_bf16(v0, h0, l0); split_bf16(v1, h1, l1);
            hu[e] = (unsigned)h0 | ((unsigned)h1 << 16);
            lu[e] = (unsigned)l0 | ((unsigned)l1 << 16);
        }
        *(uint4*)hchunk(hilo, n, fh*2)       = make_uint4(hu[0], hu[1], hu[2], hu[3]);
        *(uint4*)hchunk(hilo, n, fh*2 + 1)   = make_uint4(hu[4], hu[5], hu[6], hu[7]);
        *(uint4*)hchunk(hilo, n, 8 + fh*2)   = make_uint4(lu[0], lu[1], lu[2], lu[3]);
        *(uint4*)hchunk(hilo, n, 8 + fh*2+1) = make_uint4(lu[4], lu[5], lu[6], lu[7]);
        __syncthreads();

        // layer 2 via MFMA: 8 tiles = (rt, jt2=wg)
        const int jt2 = wg;
        floatx16 acc = {0.f,0.f,0.f,0.f,0.f,0.f,0.f,0.f,0.f,0.f,0.f,0.f,0.f,0.f,0.f,0.f};
        #pragma unroll
        for (int p = 0; p < 3; ++p) {
            const int aSel = (p == 2) ? 8 : 0;
            const int part = (p == 1) ? 1 : 0;
            short8 af[4], bf4[4];
            #pragma unroll
            for (int c = 0; c < 4; ++c) {
                af[c]  = *(const short8*)hchunk(hilo, rt*32 + lj, aSel + c*2 + half);
                bf4[c] = *(const short8*)((const short*)we2p + part*4096 + (((c*2 + half)*64) + jt2*32 + lj)*8);
            }
            #pragma unroll
            for (int c = 0; c < 4; ++c) acc = __builtin_amdgcn_mfma_f32_32x32x16_bf16(af[c], bf4[c], acc, 0, 0, 0);
        }
        const int col = jt2*32 + lj;
        const float bias = b2v[col];
        __syncthreads();   // all layer-2 hilo reads done before overwrite
        #pragma unroll
        for (int reg = 0; reg < 16; ++reg) {
            const int row = (reg & 3) + 8*(reg >> 2) + 4*half + rt*32;
            const float v = elu_f(acc[reg] + bias);
            unsigned short hb, lb;
            split_bf16(v, hb, lb);
            *(hchunk(hilo, row, col >> 3) + (col & 7))       = hb;
            *(hchunk(hilo, row, 8 + (col >> 3)) + (col & 7)) = lb;
        }
        __syncthreads();

        // sq read-back: r = node, cq = col-quarter
        const int r = t >> 2, cq = t & 3, c0 = cq*2;
        const uint4 h0 = *(const uint4*)hchunk(hilo, r, c0);
        const uint4 h1 = *(const uint4*)hchunk(hilo, r, c0+1);
        const uint4 l0 = *(const uint4*)hchunk(hilo, r, 8+c0);
        const uint4 l1 = *(const uint4*)hchunk(hilo, r, 8+c0+1);
        float s = 0.0f;
        const unsigned hh[8] = {h0.x,h0.y,h0.z,h0.w,h1.x,h1.y,h1.z,h1.w};
        const unsigned ll[8] = {l0.x,l0.y,l0.z,l0.w,l1.x,l1.y,l1.z,l1.w};
        #pragma unroll
        for (int e = 0; e < 8; ++e) {
            const float va = bf_lo(hh[e]) + bf_lo(ll[e]);
            const float vb = bf_hi(hh[e]) + bf_hi(ll[e]);
            s = fmaf(va, va, s); s = fmaf(vb, vb, s);
        }
        s += __shfl_xor(s, 1);
        s += __shfl_xor(s, 2);
        if (cq == 0) sqs[r] = s;
        __syncthreads();
    }

    // ================= 3 conv layers =================
    #pragma unroll 1
    for (int L = 0; L < 3; ++L) {
        const unsigned short* wpl = wp + L*16384;
        const float* bcl = (L == 0) ? bc1 : (L == 1) ? bc2 : bc3;

        // ---- Gram rounds + batched-bitonic top-k ----
        unsigned xk[32];
        #pragma unroll
        for (int s = 0; s < 24; ++s) xk[s] = 0xFFFFFFFFu;

        #pragma unroll 1
        for (int jt = 0; jt < 4; ++jt) {
            if (wg == (jt & 1)) {
                floatx16 acc = {0.f,0.f,0.f,0.f,0.f,0.f,0.f,0.f,0.f,0.f,0.f,0.f,0.f,0.f,0.f,0.f};
                #pragma unroll
                for (int p = 0; p < 3; ++p) {
                    const int aSel = (p == 2) ? 8 : 0;
                    const int bSel = (p == 1) ? 8 : 0;
                    short8 af[4], bf4[4];
                    #pragma unroll
                    for (int c = 0; c < 4; ++c) {
                        af[c]  = *(const short8*)hchunk(hilo, rt*32 + lj, aSel + c*2 + half);
                        bf4[c] = *(const short8*)hchunk(hilo, jt*32 + lj, bSel + c*2 + half);
                    }
                    #pragma unroll
                    for (int c = 0; c < 4; ++c) acc = __builtin_amdgcn_mfma_f32_32x32x16_bf16(af[c], bf4[c], acc, 0, 0, 0);
                }
                const unsigned jg = (unsigned)(jt*32 + lj);
                const float sqj = sqs[jg];
                #pragma unroll
                for (int reg = 0; reg < 16; ++reg) {
                    const int i = (reg & 3) + 8*(reg >> 2) + 4*half + rt*32;
                    float d = fmaf(-2.0f, acc[reg], sqs[i] + sqj);
                    d = fmaxf(d, 0.0f);
                    keys[i*36 + lj] = (__float_as_uint(d) & 0xFFFFFF80u) | jg;
                }
            }
            __syncthreads();
            {
                const unsigned* kr = keys + i2*36 + s4*8;
                const uint4 k0 = *(const uint4*)kr;
                const uint4 k1 = *(const uint4*)(kr + 4);
                unsigned y[8] = {k0.x, k0.y, k0.z, k0.w, k1.x, k1.y, k1.z, k1.w};
                sort8_asc(y);
                #pragma unroll
                for (int e = 0; e < 8; ++e) xk[24+e] = y[7-e];
                merge_top24(xk);
            }
            __syncthreads();
        }

        // ---- merge the 4 per-row lists into s4==0, emit nnidx ----
        #pragma unroll 1
        for (int src = 1; src < 4; ++src) {
            if (s4 == src) {
                #pragma unroll
                for (int e = 0; e < 24; ++e) keys[i2*36 + 12 + e] = xk[e];
            }
            __syncthreads();
            if (s4 == 0) {
                #pragma unroll 1
                for (int b = 0; b < 3; ++b) {
                    #pragma unroll
                    for (int e = 0; e < 8; ++e) xk[24+e] = keys[i2*36 + 12 + b*8 + (7-e)];
                    merge_top24(xk);
                }
            }
            __syncthreads();
        }
        if (s4 == 0) {
            #pragma unroll
            for (int c = 0; c < 6; ++c)
                nnidx[i2*6 + c] = (xk[c*4] & 127u) | ((xk[c*4+1] & 127u) << 8)
                                | ((xk[c*4+2] & 127u) << 16) | ((xk[c*4+3] & 127u) << 24);
        }
        __syncthreads();   // keys dead -> bs may overwrite; nnidx visible

        // ---- ab-GEMM: waves 0-3 -> a (global, +bias), waves 4-7 -> b (LDS bf16) ----
        unsigned short* bs = (unsigned short*)arena;   // [128][68] bf16
        {
            short8 afr[8];
            #pragma unroll
            for (int sel = 0; sel < 2; ++sel)
                #pragma unroll
                for (int c = 0; c < 4; ++c)
                    afr[sel*4+c] = *(const short8*)hchunk(hilo, rt*32 + lj, sel*8 + c*2 + half);

            #pragma unroll 1
            for (int q2 = 0; q2 < 2; ++q2) {
                const int jt = wg*2 + q2;
                short8 bfr[8];
                #pragma unroll
                for (int part = 0; part < 2; ++part)
                    #pragma unroll
                    for (int c = 0; c < 4; ++c)
                        bfr[part*4+c] = *(const short8*)((const short*)wpl + part*8192 + (((c*2 + half)*128) + jt*32 + lj)*8);
                floatx16 acc = {0.f,0.f,0.f,0.f,0.f,0.f,0.f,0.f,0.f,0.f,0.f,0.f,0.f,0.f,0.f,0.f};
                #pragma unroll
                for (int c = 0; c < 4; ++c) acc = __builtin_amdgcn_mfma_f32_32x32x16_bf16(afr[c],   bfr[c],   acc, 0, 0, 0);
                #pragma unroll
                for (int c = 0; c < 4; ++c) acc = __builtin_amdgcn_mfma_f32_32x32x16_bf16(afr[c],   bfr[4+c], acc, 0, 0, 0);
                #pragma unroll
                for (int c = 0; c < 4; ++c) acc = __builtin_amdgcn_mfma_f32_32x32x16_bf16(afr[4+c], bfr[c],   acc, 0, 0, 0);

                if (wg == 0) {
                    const int col = jt*32 + lj;
                    const float bias = bcl[col];
                    #pragma unroll
                    for (int reg = 0; reg < 16; ++reg) {
                        const int row = (reg & 3) + 8*(reg >> 2) + 4*half + rt*32;
                        ag[(size_t)row*64 + col] = acc[reg] + bias;
                    }
                } else {
                    const int colb = q2*32 + lj;
                    #pragma unroll
                    for (int reg = 0; reg < 16; ++reg) {
                        const int row = (reg & 3) + 8*(reg >> 2) + 4*half + rt*32;
                        bs[row*68 + colb] = bf_rne(acc[reg]);
                    }
                }
            }
        }
        __syncthreads();   // bs/ag ready; hilo reads done -> may be rewritten

        // ---- aggregation: out = elu(a + max_nn b); emit next hilo+sq, or pooled on last layer ----
        {
            const int q = lane >> 4, fq = lane & 15;
            float4 psum = make_float4(0.f, 0.f, 0.f, 0.f);
            #pragma unroll 1
            for (int rg = 0; rg < 4; ++rg) {
                const int row = w*16 + rg*4 + q;
                float4 m = make_float4(-3e38f, -3e38f, -3e38f, -3e38f);
                #pragma unroll
                for (int c = 0; c < 6; ++c) {
                    const unsigned pk = nnidx[row*6 + c];
                    #pragma unroll
                    for (int e = 0; e < 4; ++e) {
                        const int j = (pk >> (8*e)) & 127;
                        const uint2 bb = *(const uint2*)(bs + j*68 + fq*4);
                        m.x = fmaxf(m.x, bf_lo(bb.x)); m.y = fmaxf(m.y, bf_hi(bb.x));
                        m.z = fmaxf(m.z, bf_lo(bb.y)); m.w = fmaxf(m.w, bf_hi(bb.y));
                    }
                }
                const float4 av = *(const float4*)(ag + (size_t)row*64 + fq*4);
                float4 o;
                o.x = elu_f(av.x + m.x); o.y = elu_f(av.y + m.y);
                o.z = elu_f(av.z + m.z); o.w = elu_f(av.w + m.w);

                if (L < 2) {
                    unsigned short hx,lx,hy,ly,hz,lz,hw2,lw2;
                    split_bf16(o.x,hx,lx); split_bf16(o.y,hy,ly);
                    split_bf16(o.z,hz,lz); split_bf16(o.w,hw2,lw2);
                    *(uint2*)(hchunk(hilo, row, fq >> 1) + (fq & 1)*4) =
                        make_uint2((unsigned)hx | ((unsigned)hy << 16), (unsigned)hz | ((unsigned)hw2 << 16));
                    *(uint2*)(hchunk(hilo, row, 8 + (fq >> 1)) + (fq & 1)*4) =
                        make_uint2((unsigned)lx | ((unsigned)ly << 16), (unsigned)lz | ((unsigned)lw2 << 16));
                    float sp = o.x*o.x + o.y*o.y + o.z*o.z + o.w*o.w;
                    sp += __shfl_xor(sp, 1);
                    sp += __shfl_xor(sp, 2);
                    sp += __shfl_xor(sp, 4);
                    sp += __shfl_xor(sp, 8);
                    if (fq == 0) sqs[row] = sp;
                } else {
                    psum.x += o.x; psum.y += o.y; psum.z += o.z; psum.w += o.w;
                }
            }
            if (L < 2) {
                __syncthreads();   // next layer sees new hilo + sqs
            } else {
                __syncthreads();   // nnidx reads done -> pool8 may alias
                float* pool8 = (float*)(arena + 18432);   // [8][64]
                psum.x += __shfl_xor(psum.x, 16); psum.y += __shfl_xor(psum.y, 16);
                psum.z += __shfl_xor(psum.z, 16); psum.w += __shfl_xor(psum.w, 16);
                psum.x += __shfl_xor(psum.x, 32); psum.y += __shfl_xor(psum.y, 32);
                psum.z += __shfl_xor(psum.z, 32); psum.w += __shfl_xor(psum.w, 32);
                if (q == 0) *(float4*)(pool8 + w*64 + fq*4) = psum;
                __syncthreads();
                if (t < 64) {
                    float s = 0.0f;
                    #pragma unroll
                    for (int k = 0; k < 8; ++k) s += pool8[k*64 + t];
                    pooled_out[(size_t)g*64 + t] = s;
                }
            }
        }
    }
}

// ---------------- head: 5-layer MLP on pooled[512][64] ----------------
__global__ __launch_bounds__(64) void head_kernel(
    const float* __restrict__ pooled_in,
    const float* __restrict__ wo1, const float* __restrict__ bo1,
    const float* __restrict__ wo2, const float* __restrict__ bo2,
    const float* __restrict__ wo3, const float* __restrict__ bo3,
    const float* __restrict__ wo4, const float* __restrict__ bo4,
    const float* __restrict__ wo5, const float* __restrict__ bo5,
    float* __restrict__ outp)
{
    __shared__ float pooled[64];
    __shared__ float o1[64];
    __shared__ float o2[32];
    __shared__ float o3[32];
    __shared__ float o4[8];
    const int g = blockIdx.x, t = threadIdx.x;

    pooled[t] = pooled_in[(size_t)g*64 + t];
    {
        float acc = bo1[t];
        #pragma unroll
        for (int k = 0; k < 64; ++k) acc = fmaf(pooled[k], wo1[k*64 + t], acc);
        o1[t] = elu_f(acc);
    }
    if (t < 32) {
        float acc = bo2[t];
        #pragma unroll
        for (int k = 0; k < 64; ++k) acc = fmaf(o1[k], wo2[k*32 + t], acc);
        o2[t] = elu_f(acc);
    }
    if (t < 32) {
        float acc = bo3[t];
        #pragma unroll
        for (int k = 0; k < 32; ++k) acc = fmaf(o2[k], wo3[k*32 + t], acc);
        o3[t] = elu_f(acc);
    }
    if (t < 8) {
        float acc = bo4[t];
        #pragma unroll
        for (int k = 0; k < 32; ++k) acc = fmaf(o3[k], wo4[k*8 + t], acc);
        o4[t] = elu_f(acc);
    }
    if (t == 0) {
        float acc = bo5[0];
        #pragma unroll
        for (int k = 0; k < 8; ++k) acc = fmaf(o4[k], wo5[k], acc);
        outp[g] = acc;
    }
}

extern "C" void kernel_launch(void* const* d_in, const int* in_sizes, int n_in,
                              void* d_out, int out_size, void* d_ws, size_t ws_size,
                              hipStream_t stream) {
    const float* x_pf = (const float*)d_in[0];
    const float* we1 = (const float*)d_in[2];
    const float* be1 = (const float*)d_in[3];
    const float* we2 = (const float*)d_in[4];
    const float* be2 = (const float*)d_in[5];
    const float* wc1 = (const float*)d_in[6];
    const float* bc1 = (const float*)d_in[7];
    const float* wc2 = (const float*)d_in[8];
    const float* bc2 = (const float*)d_in[9];
    const float* wc3 = (const float*)d_in[10];
    const float* bc3 = (const float*)d_in[11];
    const float* wo1 = (const float*)d_in[12];
    const float* bo1 = (const float*)d_in[13];
    const float* wo2 = (const float*)d_in[14];
    const float* bo2 = (const float*)d_in[15];
    const float* wo3 = (const float*)d_in[16];
    const float* bo3 = (const float*)d_in[17];
    const float* wo4 = (const float*)d_in[18];
    const float* bo4 = (const float*)d_in[19];
    const float* wo5 = (const float*)d_in[20];
    const float* bo5 = (const float*)d_in[21];

    float* out = (float*)d_out;           // [0:512) outputs, [512:) batch ids (as float)
    char* ws = (char*)d_ws;
    float* abuf   = (float*)(ws);                                  // 16 MB
    float* pooled = (float*)(ws + (size_t)16*1024*1024);           // 128 KB
    unsigned short* wpack = (unsigned short*)(ws + (size_t)17*1024*1024);  // 112 KB

    pack_w<<<112, 256, 0, stream>>>(wc1, wc2, wc3, we2, wpack);

    conv_all<<<NG, 512, 0, stream>>>(x_pf, wpack, bc1, bc2, bc3,
        we1, be1, wpack + 49152, be2, abuf, pooled, out + NG);

    head_kernel<<<NG, 64, 0, stream>>>(pooled, wo1, bo1, wo2, bo2, wo3, bo3, wo4, bo4, wo5, bo5, out);
}